// Round 10
// baseline (464.802 us; speedup 1.0000x reference)
//
#include <hip/hip_runtime.h>

#define HEADS 16
#define DH    64
#define NA    2048
#define NX    2048
#define NTOT  4096
#define DIMK  1024
#define NQKV  3072
#define SEG   256
#define NSEG  16

typedef float          f32x4  __attribute__((ext_vector_type(4)));
typedef short          bf16x8 __attribute__((ext_vector_type(8)));
typedef unsigned int   u32x4  __attribute__((ext_vector_type(4)));

// f32 -> bf16 bits, round-to-nearest-even (finite inputs)
__device__ __forceinline__ unsigned short f2bf(float f){
  unsigned int u = __builtin_bit_cast(unsigned int, f);
  unsigned int r = 0x7fffu + ((u >> 16) & 1u);
  return (unsigned short)((u + r) >> 16);
}

__global__ __launch_bounds__(256) void zero_kernel(float* __restrict__ out, int n){
  int i = blockIdx.x * 256 + threadIdx.x;
  if (i < n) out[i] = 0.f;
}

// ---------------- K0a: f32 -> bf16 elementwise ----------------
__global__ __launch_bounds__(256) void cvt_kernel(const float* __restrict__ src,
                                                  unsigned short* __restrict__ dst, int n4){
  int i = blockIdx.x * 256 + threadIdx.x;
  if (i >= n4) return;
  float4 v = ((const float4*)src)[i];
  ushort4 o;
  o.x = f2bf(v.x); o.y = f2bf(v.y); o.z = f2bf(v.z); o.w = f2bf(v.w);
  ((ushort4*)dst)[i] = o;
}

// ---------------- K0b: W [DIMK][NQKV] f32 -> WT [NQKV][DIMK] bf16 ----------------
__global__ __launch_bounds__(256) void wtr_kernel(const float* __restrict__ W,
                                                  unsigned short* __restrict__ WT){
  __shared__ float tile[32][33];
  int c0 = blockIdx.x * 32, k0 = blockIdx.y * 32;
  int tx = threadIdx.x, ty = threadIdx.y;
  #pragma unroll
  for (int i = 0; i < 32; i += 8) tile[ty+i][tx] = W[(size_t)(k0+ty+i)*NQKV + c0 + tx];
  __syncthreads();
  #pragma unroll
  for (int i = 0; i < 32; i += 8) WT[(size_t)(c0+ty+i)*DIMK + k0 + tx] = f2bf(tile[tx][ty+i]);
}

// ---------------- K1: bf16 MFMA GEMM, scatter into q/k/v (b,h,n,d) f32 ----------------
__global__ __launch_bounds__(256,2) void gemm_qkv_kernel(
    const unsigned short* __restrict__ Xb, const unsigned short* __restrict__ WT,
    float* __restrict__ qw, float* __restrict__ kw, float* __restrict__ vw, const int n_off)
{
  __shared__ __align__(16) unsigned short As[128*32];
  __shared__ __align__(16) unsigned short Bs[128*32];
  const int tid  = threadIdx.x;
  const int lane = tid & 63, w = tid >> 6;
  const int wr = w >> 1, wc = w & 1;
  const int m0 = blockIdx.y * 128, c0 = blockIdx.x * 128;

  f32x4 acc[4][4] = {};

  for (int k0 = 0; k0 < DIMK; k0 += 32){
    __syncthreads();
    #pragma unroll
    for (int cc = 0; cc < 2; cc++){
      const int c = tid*2 + cc;
      const int row = c >> 2, slot = c & 3;
      const int gs = slot ^ (row & 3);
      *(u32x4*)(&As[row*32 + slot*8]) = *(const u32x4*)(Xb + (size_t)(m0+row)*DIMK + k0 + gs*8);
      *(u32x4*)(&Bs[row*32 + slot*8]) = *(const u32x4*)(WT + (size_t)(c0+row)*DIMK + k0 + gs*8);
    }
    __syncthreads();
    bf16x8 af[4], bf[4];
    const int kc = lane >> 4;
    #pragma unroll
    for (int m = 0; m < 4; m++){
      const int r = wr*64 + m*16 + (lane & 15);
      af[m] = *(const bf16x8*)(&As[r*32 + ((kc ^ (r & 3)) * 8)]);
    }
    #pragma unroll
    for (int n = 0; n < 4; n++){
      const int r = wc*64 + n*16 + (lane & 15);
      bf[n] = *(const bf16x8*)(&Bs[r*32 + ((kc ^ (r & 3)) * 8)]);
    }
    #pragma unroll
    for (int m = 0; m < 4; m++)
      #pragma unroll
      for (int n = 0; n < 4; n++)
        acc[m][n] = __builtin_amdgcn_mfma_f32_16x16x32_bf16(af[m], bf[n], acc[m][n], 0, 0, 0);
  }

  // epilogue: D frag mapping col=lane&15, row=(lane>>4)*4+reg
  #pragma unroll
  for (int m = 0; m < 4; m++){
    #pragma unroll
    for (int r4 = 0; r4 < 4; r4++){
      const int row = m0 + wr*64 + m*16 + ((lane >> 4) * 4) + r4;
      const int bb = row >> 11, nn = row & 2047;
      #pragma unroll
      for (int n = 0; n < 4; n++){
        const int col = c0 + wc*64 + n*16 + (lane & 15);
        const int which = col >> 10;
        const int h = (col >> 6) & 15, d = col & 63;
        float* dst = (which == 0) ? qw : ((which == 1) ? kw : vw);
        dst[(((size_t)(bb*HEADS + h))*NTOT + (size_t)(nn + n_off))*DH + d] = acc[m][n][r4];
      }
    }
  }
}

// ---------------- K2: in-place mh_rmsnorm + RoPE on q,k ----------------
__global__ __launch_bounds__(256) void normrope_kernel(
    float* __restrict__ qw, float* __restrict__ kw,
    const float* __restrict__ gqx, const float* __restrict__ gkx,
    const float* __restrict__ gqa, const float* __restrict__ gka)
{
  const int tid = blockIdx.x * 256 + threadIdx.x;   // 0..262143
  const int t = tid >> 17;                          // 0=q, 1=k
  const int r = tid & 131071;                       // (b*16+h)*4096 + n
  const int n = r & 4095;
  const int h = (r >> 12) & 15;
  float* base = (t == 0 ? qw : kw) + (size_t)r * DH;
  const float* g = (t == 0) ? (n < NA ? gqa : gqx) : (n < NA ? gka : gkx);
  g += h * DH;
  float v[DH];
  #pragma unroll
  for (int i = 0; i < 16; i++){
    float4 f = ((const float4*)base)[i];
    v[4*i] = f.x; v[4*i+1] = f.y; v[4*i+2] = f.z; v[4*i+3] = f.w;
  }
  float ss = 0.f;
  #pragma unroll
  for (int d = 0; d < DH; d++) ss += v[d]*v[d];
  const float sc = 8.0f / fmaxf(sqrtf(ss), 1e-12f);
  #pragma unroll
  for (int d = 0; d < DH; d++) v[d] = v[d] * sc * g[d];
  float o[DH];
  const float fn = (float)n;
  #pragma unroll
  for (int d = 0; d < 32; d++){
    const float invf = expf(-(float)d * 0.28782313662425572f);  // 10000^(-d/32)
    float sn, cs;
    sincosf(fn * invf, &sn, &cs);
    o[d]    = v[d]*cs    - v[d+32]*sn;
    o[d+32] = v[d+32]*cs + v[d]*sn;
  }
  #pragma unroll
  for (int i = 0; i < 16; i++){
    float4 f; f.x = o[4*i]; f.y = o[4*i+1]; f.z = o[4*i+2]; f.w = o[4*i+3];
    ((float4*)base)[i] = f;
  }
}

// ---------------- K3: per-segment G_s = sk^T v (64x64), zc_s = sum sk ----------------
__global__ __launch_bounds__(256,1) void segG_kernel(const float* __restrict__ kw,
                                                     const float* __restrict__ vw,
                                                     float* __restrict__ G, float* __restrict__ zc){
  __shared__ float sk[SEG][DH];
  __shared__ float sv[SEG][DH];
  const int blk = blockIdx.x;           // bh*16 + s
  const int tid = threadIdx.x;
  const size_t segoff = ((size_t)(blk >> 4) * NTOT + (size_t)(blk & 15) * SEG) * DH;
  for (int i = tid; i < SEG*DH/4; i += 256){
    float4 kk = ((const float4*)(kw + segoff))[i];
    float4 s4;
    s4.x = kk.x > 0.f ? kk.x + 1.f : __expf(kk.x);
    s4.y = kk.y > 0.f ? kk.y + 1.f : __expf(kk.y);
    s4.z = kk.z > 0.f ? kk.z + 1.f : __expf(kk.z);
    s4.w = kk.w > 0.f ? kk.w + 1.f : __expf(kk.w);
    ((float4*)sk)[i] = s4;
    ((float4*)sv)[i] = ((const float4*)(vw + segoff))[i];
  }
  __syncthreads();
  const int d = tid >> 2, e0 = (tid & 3) * 16;
  float acc[16];
  #pragma unroll
  for (int e = 0; e < 16; e++) acc[e] = 0.f;
  float z = 0.f;
  for (int l = 0; l < SEG; l++){
    const float skd = sk[l][d];
    z += skd;
    #pragma unroll
    for (int e = 0; e < 16; e++) acc[e] += skd * sv[l][e0 + e];
  }
  float* Gout = G + (size_t)blk * DH * DH;
  #pragma unroll
  for (int e = 0; e < 16; e++) Gout[d*DH + e0 + e] = acc[e];
  if ((tid & 3) == 0) zc[(size_t)blk * DH + d] = z;
}

// ---------------- K4: exclusive prefix over segments -> Mp, zp ----------------
__global__ __launch_bounds__(256) void prefix_kernel(const float* __restrict__ G,
                                                     const float* __restrict__ zc,
                                                     float* __restrict__ Mp, float* __restrict__ zp){
  const int bh = blockIdx.x, tid = threadIdx.x;
  float run[16];
  #pragma unroll
  for (int k = 0; k < 16; k++) run[k] = 0.f;
  for (int s = 0; s < NSEG; s++){
    const size_t base = ((size_t)bh * NSEG + s) * DH * DH;
    #pragma unroll
    for (int k = 0; k < 16; k++){
      Mp[base + tid + 256*k] = run[k];
      run[k] += G[base + tid + 256*k];
    }
  }
  if (tid < DH){
    float rz = 0.f;
    for (int s = 0; s < NSEG; s++){
      zp[((size_t)bh*NSEG + s)*DH + tid] = rz;
      rz += zc[((size_t)bh*NSEG + s)*DH + tid];
    }
  }
}

// ---------------- K5: per-segment attention + memory readout -> f32 out ----------------
__global__ __launch_bounds__(256,1) void attn_kernel(
    const float* __restrict__ qw, const float* __restrict__ kw, const float* __restrict__ vw,
    const float* __restrict__ Mp, const float* __restrict__ zp, const float* __restrict__ beta,
    float* __restrict__ out)
{
  __shared__ float ks[SEG][DH];
  __shared__ float vs[SEG][DH];
  __shared__ float Ms[DH][DH];
  __shared__ float zsh[DH];
  const int blk = blockIdx.x;
  const int s = blk & 15, bh = blk >> 4;
  const int h = bh & 15, b = bh >> 4;
  const int tid = threadIdx.x;
  const size_t segoff = ((size_t)bh * NTOT + (size_t)s * SEG) * DH;

  for (int i = tid; i < SEG*DH/4; i += 256){
    ((float4*)ks)[i] = ((const float4*)(kw + segoff))[i];
    ((float4*)vs)[i] = ((const float4*)(vw + segoff))[i];
  }
  for (int i = tid; i < DH*DH/4; i += 256)
    ((float4*)Ms)[i] = ((const float4*)(Mp + (size_t)blk*DH*DH))[i];
  if (tid < DH) zsh[tid] = zp[(size_t)blk*DH + tid];
  __syncthreads();

  const float* qrow_g = qw + segoff + (size_t)tid * DH;
  float q[DH];
  #pragma unroll
  for (int i = 0; i < 16; i++){
    float4 f = ((const float4*)qrow_g)[i];
    q[4*i] = f.x; q[4*i+1] = f.y; q[4*i+2] = f.z; q[4*i+3] = f.w;
  }
  float aloc[DH];
  #pragma unroll
  for (int e = 0; e < DH; e++) aloc[e] = 0.f;
  float den = 0.f;
  const int i = tid;
  const int jmax = ((i >> 6) + 1) << 6;   // wave-uniform causal bound
  for (int j = 0; j < jmax; j++){
    float s0 = 0.f, s1 = 0.f, s2 = 0.f, s3 = 0.f;
    #pragma unroll
    for (int d = 0; d < DH; d += 4){
      s0 += q[d]  * ks[j][d];
      s1 += q[d+1]* ks[j][d+1];
      s2 += q[d+2]* ks[j][d+2];
      s3 += q[d+3]* ks[j][d+3];
    }
    const float sc = (s0+s1+s2+s3) * 0.125f;
    const float p = (j <= i) ? __expf(sc) : 0.f;
    den += p;
    #pragma unroll
    for (int e = 0; e < DH; e++) aloc[e] += p * vs[j][e];
  }
  const float g = 1.f / (1.f + expf(-beta[h]));
  const float c1 = (1.f - g) / den;
  #pragma unroll
  for (int e = 0; e < DH; e++) aloc[e] *= c1;

  // memory readout: a_mem = (sq @ M) / (sq.z + 1e-6); fold gate
  float denm = 0.f;
  #pragma unroll
  for (int d = 0; d < DH; d++){
    const float x = q[d];
    denm += (x > 0.f ? x + 1.f : __expf(x)) * zsh[d];
  }
  const float c2 = g / (denm + 1e-6f);
  for (int d = 0; d < DH; d++){
    const float x = q[d];
    const float sq = (x > 0.f ? x + 1.f : __expf(x)) * c2;
    #pragma unroll
    for (int e = 0; e < DH; e++) aloc[e] += sq * Ms[d][e];
  }

  // f32 output: out_x chunk 0 (elements [0, 4194304)), out_a chunk 1
  const int n_g = s * SEG + i;
  size_t o;
  if (n_g >= NA) o = ((size_t)b * NX + (size_t)(n_g - NA)) * 1024 + h * 64;
  else           o = 4194304u + ((size_t)b * NA + (size_t)n_g) * 1024 + h * 64;
  float* dst = out + o;
  #pragma unroll
  for (int e = 0; e < 16; e++){
    float4 f; f.x = aloc[4*e]; f.y = aloc[4*e+1]; f.z = aloc[4*e+2]; f.w = aloc[4*e+3];
    ((float4*)dst)[e] = f;
  }
}

extern "C" void kernel_launch(void* const* d_in, const int* in_sizes, int n_in,
                              void* d_out, int out_size, void* d_ws, size_t ws_size,
                              hipStream_t stream)
{
  (void)ws_size;
  // I/O-contract guard (validated): mismatch -> zero output
  const int expect[9] = {4194304, 4194304, 3145728, 3145728, 1024, 1024, 1024, 1024, 16};
  bool ok = (n_in == 9);
  if (ok) for (int i = 0; i < 9; i++) if (in_sizes[i] != expect[i]) { ok = false; break; }
  float* out = (float*)d_out;
  if (!ok){
    zero_kernel<<<dim3((out_size + 255)/256), dim3(256), 0, stream>>>(out, out_size);
    return;
  }

  const float* x    = (const float*)d_in[0];
  const float* a    = (const float*)d_in[1];
  const float* wx   = (const float*)d_in[2];
  const float* wa   = (const float*)d_in[3];
  const float* gqx  = (const float*)d_in[4];
  const float* gkx  = (const float*)d_in[5];
  const float* gqa  = (const float*)d_in[6];
  const float* gka  = (const float*)d_in[7];
  const float* beta = (const float*)d_in[8];

  char* wsb = (char*)d_ws;
  float* qw = (float*)wsb;                                   // 33,554,432 B
  float* kw = qw + 8388608;                                  // 33,554,432 B
  float* vw = kw + 8388608;                                  // 33,554,432 B
  unsigned short* Xb  = (unsigned short*)(wsb + 100663296);  //  8,388,608 B
  unsigned short* Ab  = Xb + 4194304;                        //  8,388,608 B
  unsigned short* WTx = Ab + 4194304;                        //  6,291,456 B
  unsigned short* WTa = WTx + 3145728;                       //  6,291,456 B
  float* G   = (float*)(wsb + 130023424);                    //  8,388,608 B
  float* Mp  = G + 2097152;                                  //  8,388,608 B
  float* zc  = Mp + 2097152;                                 //    131,072 B
  float* zpb = zc + 32768;                                   //    131,072 B  (total ~147 MB)

  cvt_kernel<<<dim3(4096), dim3(256), 0, stream>>>(x, Xb, 1048576);
  cvt_kernel<<<dim3(4096), dim3(256), 0, stream>>>(a, Ab, 1048576);
  wtr_kernel<<<dim3(96,32), dim3(32,8), 0, stream>>>(wx, WTx);
  wtr_kernel<<<dim3(96,32), dim3(32,8), 0, stream>>>(wa, WTa);
  // a tokens occupy concatenated positions [0,2048); x tokens [2048,4096)
  gemm_qkv_kernel<<<dim3(24,32), dim3(256), 0, stream>>>(Xb, WTx, qw, kw, vw, 2048);
  gemm_qkv_kernel<<<dim3(24,32), dim3(256), 0, stream>>>(Ab, WTa, qw, kw, vw, 0);
  normrope_kernel<<<dim3(1024), dim3(256), 0, stream>>>(qw, kw, gqx, gkx, gqa, gka);
  segG_kernel<<<dim3(512), dim3(256), 0, stream>>>(kw, vw, G, zc);
  prefix_kernel<<<dim3(32), dim3(256), 0, stream>>>(G, zc, Mp, zpb);
  attn_kernel<<<dim3(512), dim3(256), 0, stream>>>(qw, kw, vw, Mp, zpb, beta, out);
}

// Round 11
// 406.000 us; speedup vs baseline: 1.1448x; 1.1448x over previous
//
#include <hip/hip_runtime.h>

#define HEADS 16
#define DH    64
#define NA    2048
#define NX    2048
#define NTOT  4096
#define DIMK  1024
#define NQKV  3072
#define SEG   256
#define NSEG  16

typedef float          f32x4  __attribute__((ext_vector_type(4)));
typedef short          bf16x8 __attribute__((ext_vector_type(8)));
typedef unsigned int   u32x4  __attribute__((ext_vector_type(4)));

// f32 -> bf16 bits, round-to-nearest-even (finite inputs)
__device__ __forceinline__ unsigned short f2bf(float f){
  unsigned int u = __builtin_bit_cast(unsigned int, f);
  unsigned int r = 0x7fffu + ((u >> 16) & 1u);
  return (unsigned short)((u + r) >> 16);
}

__global__ __launch_bounds__(256) void zero_kernel(float* __restrict__ out, int n){
  int i = blockIdx.x * 256 + threadIdx.x;
  if (i < n) out[i] = 0.f;
}

// ---------------- K0a: f32 -> bf16 elementwise ----------------
__global__ __launch_bounds__(256) void cvt_kernel(const float* __restrict__ src,
                                                  unsigned short* __restrict__ dst, int n4){
  int i = blockIdx.x * 256 + threadIdx.x;
  if (i >= n4) return;
  float4 v = ((const float4*)src)[i];
  ushort4 o;
  o.x = f2bf(v.x); o.y = f2bf(v.y); o.z = f2bf(v.z); o.w = f2bf(v.w);
  ((ushort4*)dst)[i] = o;
}

// ---------------- K0b: W [DIMK][NQKV] f32 -> WT [NQKV][DIMK] bf16 ----------------
__global__ __launch_bounds__(256) void wtr_kernel(const float* __restrict__ W,
                                                  unsigned short* __restrict__ WT){
  __shared__ float tile[32][33];
  int c0 = blockIdx.x * 32, k0 = blockIdx.y * 32;
  int tx = threadIdx.x, ty = threadIdx.y;
  #pragma unroll
  for (int i = 0; i < 32; i += 8) tile[ty+i][tx] = W[(size_t)(k0+ty+i)*NQKV + c0 + tx];
  __syncthreads();
  #pragma unroll
  for (int i = 0; i < 32; i += 8) WT[(size_t)(c0+ty+i)*DIMK + k0 + tx] = f2bf(tile[tx][ty+i]);
}

// ---------------- K1: bf16 MFMA GEMM, scatter into q/k/v (b,h,n,d) f32 ----------------
__global__ __launch_bounds__(256,2) void gemm_qkv_kernel(
    const unsigned short* __restrict__ Xb, const unsigned short* __restrict__ WT,
    float* __restrict__ qw, float* __restrict__ kw, float* __restrict__ vw, const int n_off)
{
  __shared__ __align__(16) unsigned short As[128*32];
  __shared__ __align__(16) unsigned short Bs[128*32];
  const int tid  = threadIdx.x;
  const int lane = tid & 63, w = tid >> 6;
  const int wr = w >> 1, wc = w & 1;
  const int m0 = blockIdx.y * 128, c0 = blockIdx.x * 128;

  f32x4 acc[4][4] = {};

  for (int k0 = 0; k0 < DIMK; k0 += 32){
    __syncthreads();
    #pragma unroll
    for (int cc = 0; cc < 2; cc++){
      const int c = tid*2 + cc;
      const int row = c >> 2, slot = c & 3;
      const int gs = slot ^ (row & 3);
      *(u32x4*)(&As[row*32 + slot*8]) = *(const u32x4*)(Xb + (size_t)(m0+row)*DIMK + k0 + gs*8);
      *(u32x4*)(&Bs[row*32 + slot*8]) = *(const u32x4*)(WT + (size_t)(c0+row)*DIMK + k0 + gs*8);
    }
    __syncthreads();
    bf16x8 af[4], bf[4];
    const int kc = lane >> 4;
    #pragma unroll
    for (int m = 0; m < 4; m++){
      const int r = wr*64 + m*16 + (lane & 15);
      af[m] = *(const bf16x8*)(&As[r*32 + ((kc ^ (r & 3)) * 8)]);
    }
    #pragma unroll
    for (int n = 0; n < 4; n++){
      const int r = wc*64 + n*16 + (lane & 15);
      bf[n] = *(const bf16x8*)(&Bs[r*32 + ((kc ^ (r & 3)) * 8)]);
    }
    #pragma unroll
    for (int m = 0; m < 4; m++)
      #pragma unroll
      for (int n = 0; n < 4; n++)
        acc[m][n] = __builtin_amdgcn_mfma_f32_16x16x32_bf16(af[m], bf[n], acc[m][n], 0, 0, 0);
  }

  // epilogue: D frag mapping col=lane&15, row=(lane>>4)*4+reg
  #pragma unroll
  for (int m = 0; m < 4; m++){
    #pragma unroll
    for (int r4 = 0; r4 < 4; r4++){
      const int row = m0 + wr*64 + m*16 + ((lane >> 4) * 4) + r4;
      const int bb = row >> 11, nn = row & 2047;
      #pragma unroll
      for (int n = 0; n < 4; n++){
        const int col = c0 + wc*64 + n*16 + (lane & 15);
        const int which = col >> 10;
        const int h = (col >> 6) & 15, d = col & 63;
        float* dst = (which == 0) ? qw : ((which == 1) ? kw : vw);
        dst[(((size_t)(bb*HEADS + h))*NTOT + (size_t)(nn + n_off))*DH + d] = acc[m][n][r4];
      }
    }
  }
}

// ---------------- K2: in-place mh_rmsnorm + RoPE on q,k ----------------
__global__ __launch_bounds__(256) void normrope_kernel(
    float* __restrict__ qw, float* __restrict__ kw,
    const float* __restrict__ gqx, const float* __restrict__ gkx,
    const float* __restrict__ gqa, const float* __restrict__ gka)
{
  const int tid = blockIdx.x * 256 + threadIdx.x;   // 0..262143
  const int t = tid >> 17;                          // 0=q, 1=k
  const int r = tid & 131071;                       // (b*16+h)*4096 + n
  const int n = r & 4095;
  const int h = (r >> 12) & 15;
  float* base = (t == 0 ? qw : kw) + (size_t)r * DH;
  const float* g = (t == 0) ? (n < NA ? gqa : gqx) : (n < NA ? gka : gkx);
  g += h * DH;
  float v[DH];
  #pragma unroll
  for (int i = 0; i < 16; i++){
    float4 f = ((const float4*)base)[i];
    v[4*i] = f.x; v[4*i+1] = f.y; v[4*i+2] = f.z; v[4*i+3] = f.w;
  }
  float ss = 0.f;
  #pragma unroll
  for (int d = 0; d < DH; d++) ss += v[d]*v[d];
  const float sc = 8.0f / fmaxf(sqrtf(ss), 1e-12f);
  #pragma unroll
  for (int d = 0; d < DH; d++) v[d] = v[d] * sc * g[d];
  float o[DH];
  const float fn = (float)n;
  #pragma unroll
  for (int d = 0; d < 32; d++){
    const float invf = expf(-(float)d * 0.28782313662425572f);  // 10000^(-d/32)
    float sn, cs;
    sincosf(fn * invf, &sn, &cs);
    o[d]    = v[d]*cs    - v[d+32]*sn;
    o[d+32] = v[d+32]*cs + v[d]*sn;
  }
  #pragma unroll
  for (int i = 0; i < 16; i++){
    float4 f; f.x = o[4*i]; f.y = o[4*i+1]; f.z = o[4*i+2]; f.w = o[4*i+3];
    ((float4*)base)[i] = f;
  }
}

// ---------------- K3: per-segment G_s = sk^T v (64x64), zc_s = sum sk ----------------
__global__ __launch_bounds__(256,1) void segG_kernel(const float* __restrict__ kw,
                                                     const float* __restrict__ vw,
                                                     float* __restrict__ G, float* __restrict__ zc){
  __shared__ float sk[SEG][DH];
  __shared__ float sv[SEG][DH];
  const int blk = blockIdx.x;           // bh*16 + s
  const int tid = threadIdx.x;
  const size_t segoff = ((size_t)(blk >> 4) * NTOT + (size_t)(blk & 15) * SEG) * DH;
  for (int i = tid; i < SEG*DH/4; i += 256){
    float4 kk = ((const float4*)(kw + segoff))[i];
    float4 s4;
    s4.x = kk.x > 0.f ? kk.x + 1.f : __expf(kk.x);
    s4.y = kk.y > 0.f ? kk.y + 1.f : __expf(kk.y);
    s4.z = kk.z > 0.f ? kk.z + 1.f : __expf(kk.z);
    s4.w = kk.w > 0.f ? kk.w + 1.f : __expf(kk.w);
    ((float4*)sk)[i] = s4;
    ((float4*)sv)[i] = ((const float4*)(vw + segoff))[i];
  }
  __syncthreads();
  const int d = tid >> 2, e0 = (tid & 3) * 16;
  float acc[16];
  #pragma unroll
  for (int e = 0; e < 16; e++) acc[e] = 0.f;
  float z = 0.f;
  for (int l = 0; l < SEG; l++){
    const float skd = sk[l][d];
    z += skd;
    #pragma unroll
    for (int e = 0; e < 16; e++) acc[e] += skd * sv[l][e0 + e];
  }
  float* Gout = G + (size_t)blk * DH * DH;
  #pragma unroll
  for (int e = 0; e < 16; e++) Gout[d*DH + e0 + e] = acc[e];
  if ((tid & 3) == 0) zc[(size_t)blk * DH + d] = z;
}

// ---------------- K4: exclusive prefix over segments -> Mp, zp ----------------
__global__ __launch_bounds__(256) void prefix_kernel(const float* __restrict__ G,
                                                     const float* __restrict__ zc,
                                                     float* __restrict__ Mp, float* __restrict__ zp){
  const int bh = blockIdx.x, tid = threadIdx.x;
  float run[16];
  #pragma unroll
  for (int k = 0; k < 16; k++) run[k] = 0.f;
  for (int s = 0; s < NSEG; s++){
    const size_t base = ((size_t)bh * NSEG + s) * DH * DH;
    #pragma unroll
    for (int k = 0; k < 16; k++){
      Mp[base + tid + 256*k] = run[k];
      run[k] += G[base + tid + 256*k];
    }
  }
  if (tid < DH){
    float rz = 0.f;
    for (int s = 0; s < NSEG; s++){
      zp[((size_t)bh*NSEG + s)*DH + tid] = rz;
      rz += zc[((size_t)bh*NSEG + s)*DH + tid];
    }
  }
}

// ---------------- K5: per-segment attention + memory readout -> f32 out ----------------
// 1024 threads: thread = (row = tid>>2, sub = tid&3); sub owns dims [sub*16, sub*16+16).
// Dot partials combined via __shfl_xor within the lane-quad. 4 waves/SIMD for latency hiding.
__global__ __launch_bounds__(1024,1) void attn_kernel(
    const float* __restrict__ qw, const float* __restrict__ kw, const float* __restrict__ vw,
    const float* __restrict__ Mp, const float* __restrict__ zp, const float* __restrict__ beta,
    float* __restrict__ out)
{
  __shared__ float ks[SEG][DH];
  __shared__ float vs[SEG][DH];
  __shared__ float Ms[DH][DH];
  __shared__ float zsh[DH];
  const int blk = blockIdx.x;
  const int s = blk & 15, bh = blk >> 4;
  const int h = bh & 15, b = bh >> 4;
  const int tid = threadIdx.x;
  const int row = tid >> 2, sub = tid & 3;
  const int e0 = sub * 16;
  const size_t segoff = ((size_t)bh * NTOT + (size_t)s * SEG) * DH;

  for (int i = tid; i < SEG*DH/4; i += 1024){
    ((float4*)ks)[i] = ((const float4*)(kw + segoff))[i];
    ((float4*)vs)[i] = ((const float4*)(vw + segoff))[i];
  }
  for (int i = tid; i < DH*DH/4; i += 1024)
    ((float4*)Ms)[i] = ((const float4*)(Mp + (size_t)blk*DH*DH))[i];
  if (tid < DH) zsh[tid] = zp[(size_t)blk*DH + tid];
  __syncthreads();

  // q slice for the dot (this sub's 16 dims)
  const float* qrow_g = qw + segoff + (size_t)row * DH;
  float q[16];
  #pragma unroll
  for (int i = 0; i < 4; i++){
    float4 f = ((const float4*)(qrow_g + e0))[i];
    q[4*i] = f.x; q[4*i+1] = f.y; q[4*i+2] = f.z; q[4*i+3] = f.w;
  }

  float ol[16];
  #pragma unroll
  for (int e = 0; e < 16; e++) ol[e] = 0.f;
  float den = 0.f;
  const int jmax = ((row >> 6) + 1) << 6;   // wave-uniform causal bound
  for (int j = 0; j < jmax; j++){
    float s0 = 0.f, s1 = 0.f, s2 = 0.f, s3 = 0.f;
    #pragma unroll
    for (int d = 0; d < 16; d += 4){
      s0 += q[d]  * ks[j][e0 + d];
      s1 += q[d+1]* ks[j][e0 + d+1];
      s2 += q[d+2]* ks[j][e0 + d+2];
      s3 += q[d+3]* ks[j][e0 + d+3];
    }
    float sd = (s0 + s1) + (s2 + s3);
    sd += __shfl_xor(sd, 1, 64);
    sd += __shfl_xor(sd, 2, 64);
    const float p = (j <= row) ? __expf(sd * 0.125f) : 0.f;
    den += p;
    #pragma unroll
    for (int e = 0; e < 16; e++) ol[e] += p * vs[j][e0 + e];
  }
  const float g = 1.f / (1.f + expf(-beta[h]));
  const float c1 = (1.f - g) / den;
  #pragma unroll
  for (int e = 0; e < 16; e++) ol[e] *= c1;

  // memory term: one pass over d accumulating denm and unscaled macc
  float macc[16];
  #pragma unroll
  for (int e = 0; e < 16; e++) macc[e] = 0.f;
  float denm = 0.f;
  for (int i = 0; i < 16; i++){
    float4 f = ((const float4*)qrow_g)[i];   // full q row (L1-hot)
    #pragma unroll
    for (int c = 0; c < 4; c++){
      const float x = (c == 0) ? f.x : (c == 1) ? f.y : (c == 2) ? f.z : f.w;
      const float sq = (x > 0.f) ? x + 1.f : __expf(x);
      const int d = i*4 + c;
      denm += sq * zsh[d];
      #pragma unroll
      for (int e = 0; e < 16; e++) macc[e] += sq * Ms[d][e0 + e];
    }
  }
  const float c2 = g / (denm + 1e-6f);
  #pragma unroll
  for (int e = 0; e < 16; e++) ol[e] += c2 * macc[e];

  // f32 output: out_x chunk 0 (elements [0, 4194304)), out_a chunk 1
  const int n_g = s * SEG + row;
  size_t o;
  if (n_g >= NA) o = ((size_t)b * NX + (size_t)(n_g - NA)) * 1024 + h * 64;
  else           o = 4194304u + ((size_t)b * NA + (size_t)n_g) * 1024 + h * 64;
  float* dst = out + o + e0;
  #pragma unroll
  for (int e = 0; e < 4; e++){
    float4 f; f.x = ol[4*e]; f.y = ol[4*e+1]; f.z = ol[4*e+2]; f.w = ol[4*e+3];
    ((float4*)dst)[e] = f;
  }
}

extern "C" void kernel_launch(void* const* d_in, const int* in_sizes, int n_in,
                              void* d_out, int out_size, void* d_ws, size_t ws_size,
                              hipStream_t stream)
{
  (void)ws_size;
  // I/O-contract guard (validated): mismatch -> zero output
  const int expect[9] = {4194304, 4194304, 3145728, 3145728, 1024, 1024, 1024, 1024, 16};
  bool ok = (n_in == 9);
  if (ok) for (int i = 0; i < 9; i++) if (in_sizes[i] != expect[i]) { ok = false; break; }
  float* out = (float*)d_out;
  if (!ok){
    zero_kernel<<<dim3((out_size + 255)/256), dim3(256), 0, stream>>>(out, out_size);
    return;
  }

  const float* x    = (const float*)d_in[0];
  const float* a    = (const float*)d_in[1];
  const float* wx   = (const float*)d_in[2];
  const float* wa   = (const float*)d_in[3];
  const float* gqx  = (const float*)d_in[4];
  const float* gkx  = (const float*)d_in[5];
  const float* gqa  = (const float*)d_in[6];
  const float* gka  = (const float*)d_in[7];
  const float* beta = (const float*)d_in[8];

  char* wsb = (char*)d_ws;
  float* qw = (float*)wsb;                                   // 33,554,432 B
  float* kw = qw + 8388608;                                  // 33,554,432 B
  float* vw = kw + 8388608;                                  // 33,554,432 B
  unsigned short* Xb  = (unsigned short*)(wsb + 100663296);  //  8,388,608 B
  unsigned short* Ab  = Xb + 4194304;                        //  8,388,608 B
  unsigned short* WTx = Ab + 4194304;                        //  6,291,456 B
  unsigned short* WTa = WTx + 3145728;                       //  6,291,456 B
  float* G   = (float*)(wsb + 130023424);                    //  8,388,608 B
  float* Mp  = G + 2097152;                                  //  8,388,608 B
  float* zc  = Mp + 2097152;                                 //    131,072 B
  float* zpb = zc + 32768;                                   //    131,072 B  (total ~147 MB)

  cvt_kernel<<<dim3(4096), dim3(256), 0, stream>>>(x, Xb, 1048576);
  cvt_kernel<<<dim3(4096), dim3(256), 0, stream>>>(a, Ab, 1048576);
  wtr_kernel<<<dim3(96,32), dim3(32,8), 0, stream>>>(wx, WTx);
  wtr_kernel<<<dim3(96,32), dim3(32,8), 0, stream>>>(wa, WTa);
  // a tokens occupy concatenated positions [0,2048); x tokens [2048,4096)
  gemm_qkv_kernel<<<dim3(24,32), dim3(256), 0, stream>>>(Xb, WTx, qw, kw, vw, 2048);
  gemm_qkv_kernel<<<dim3(24,32), dim3(256), 0, stream>>>(Ab, WTa, qw, kw, vw, 0);
  normrope_kernel<<<dim3(1024), dim3(256), 0, stream>>>(qw, kw, gqx, gkx, gqa, gka);
  segG_kernel<<<dim3(512), dim3(256), 0, stream>>>(kw, vw, G, zc);
  prefix_kernel<<<dim3(32), dim3(256), 0, stream>>>(G, zc, Mp, zpb);
  attn_kernel<<<dim3(512), dim3(1024), 0, stream>>>(qw, kw, vw, Mp, zpb, beta, out);
}

// Round 13
// 267.278 us; speedup vs baseline: 1.7390x; 1.5190x over previous
//
#include <hip/hip_runtime.h>

#define HEADS 16
#define DH    64
#define NA    2048
#define NX    2048
#define NTOT  4096
#define DIMK  1024
#define NQKV  3072
#define SEG   256
#define NSEG  16

typedef float          f32x4  __attribute__((ext_vector_type(4)));
typedef short          bf16x8 __attribute__((ext_vector_type(8)));
typedef unsigned int   u32x4  __attribute__((ext_vector_type(4)));

// f32 -> bf16 bits, round-to-nearest-even (finite inputs)
__device__ __forceinline__ unsigned short f2bf(float f){
  unsigned int u = __builtin_bit_cast(unsigned int, f);
  unsigned int r = 0x7fffu + ((u >> 16) & 1u);
  return (unsigned short)((u + r) >> 16);
}

__global__ __launch_bounds__(256) void zero_kernel(float* __restrict__ out, int n){
  int i = blockIdx.x * 256 + threadIdx.x;
  if (i < n) out[i] = 0.f;
}

// ---------------- K0a: f32 -> bf16 elementwise ----------------
__global__ __launch_bounds__(256) void cvt_kernel(const float* __restrict__ src,
                                                  unsigned short* __restrict__ dst, int n4){
  int i = blockIdx.x * 256 + threadIdx.x;
  if (i >= n4) return;
  float4 v = ((const float4*)src)[i];
  ushort4 o;
  o.x = f2bf(v.x); o.y = f2bf(v.y); o.z = f2bf(v.z); o.w = f2bf(v.w);
  ((ushort4*)dst)[i] = o;
}

// ---------------- K0b: W [DIMK][NQKV] f32 -> WT [NQKV][DIMK] bf16 ----------------
__global__ __launch_bounds__(256) void wtr_kernel(const float* __restrict__ W,
                                                  unsigned short* __restrict__ WT){
  __shared__ float tile[32][33];
  int c0 = blockIdx.x * 32, k0 = blockIdx.y * 32;
  int tx = threadIdx.x, ty = threadIdx.y;
  #pragma unroll
  for (int i = 0; i < 32; i += 8) tile[ty+i][tx] = W[(size_t)(k0+ty+i)*NQKV + c0 + tx];
  __syncthreads();
  #pragma unroll
  for (int i = 0; i < 32; i += 8) WT[(size_t)(c0+ty+i)*DIMK + k0 + tx] = f2bf(tile[tx][ty+i]);
}

// ---------------- K0c: vw (b,h,n,d) f32 -> vt (b,h,d,n) bf16 ----------------
__global__ __launch_bounds__(256) void vtr_kernel(const float* __restrict__ vw,
                                                  unsigned short* __restrict__ vt){
  __shared__ float tile[32][33];
  const int nt = blockIdx.x, dt = blockIdx.y, bh = blockIdx.z;
  const int tx = threadIdx.x, ty = threadIdx.y;
  const size_t base = (size_t)bh * NTOT * DH;
  #pragma unroll
  for (int i = 0; i < 32; i += 8)
    tile[ty+i][tx] = vw[base + (size_t)(nt*32 + ty+i)*DH + dt*32 + tx];
  __syncthreads();
  #pragma unroll
  for (int i = 0; i < 32; i += 8)
    vt[(size_t)bh*DH*NTOT + (size_t)(dt*32 + ty+i)*NTOT + nt*32 + tx] = f2bf(tile[tx][ty+i]);
}

// ---------------- K1: bf16 MFMA GEMM, scatter into q/k/v (b,h,n,d) f32 ----------------
__global__ __launch_bounds__(256,2) void gemm_qkv_kernel(
    const unsigned short* __restrict__ Xb, const unsigned short* __restrict__ WT,
    float* __restrict__ qw, float* __restrict__ kw, float* __restrict__ vw, const int n_off)
{
  __shared__ __align__(16) unsigned short As[128*32];
  __shared__ __align__(16) unsigned short Bs[128*32];
  const int tid  = threadIdx.x;
  const int lane = tid & 63, w = tid >> 6;
  const int wr = w >> 1, wc = w & 1;
  const int m0 = blockIdx.y * 128, c0 = blockIdx.x * 128;

  f32x4 acc[4][4] = {};

  for (int k0 = 0; k0 < DIMK; k0 += 32){
    __syncthreads();
    #pragma unroll
    for (int cc = 0; cc < 2; cc++){
      const int c = tid*2 + cc;
      const int row = c >> 2, slot = c & 3;
      const int gs = slot ^ (row & 3);
      *(u32x4*)(&As[row*32 + slot*8]) = *(const u32x4*)(Xb + (size_t)(m0+row)*DIMK + k0 + gs*8);
      *(u32x4*)(&Bs[row*32 + slot*8]) = *(const u32x4*)(WT + (size_t)(c0+row)*DIMK + k0 + gs*8);
    }
    __syncthreads();
    bf16x8 af[4], bf[4];
    const int kc = lane >> 4;
    #pragma unroll
    for (int m = 0; m < 4; m++){
      const int r = wr*64 + m*16 + (lane & 15);
      af[m] = *(const bf16x8*)(&As[r*32 + ((kc ^ (r & 3)) * 8)]);
    }
    #pragma unroll
    for (int n = 0; n < 4; n++){
      const int r = wc*64 + n*16 + (lane & 15);
      bf[n] = *(const bf16x8*)(&Bs[r*32 + ((kc ^ (r & 3)) * 8)]);
    }
    #pragma unroll
    for (int m = 0; m < 4; m++)
      #pragma unroll
      for (int n = 0; n < 4; n++)
        acc[m][n] = __builtin_amdgcn_mfma_f32_16x16x32_bf16(af[m], bf[n], acc[m][n], 0, 0, 0);
  }

  #pragma unroll
  for (int m = 0; m < 4; m++){
    #pragma unroll
    for (int r4 = 0; r4 < 4; r4++){
      const int row = m0 + wr*64 + m*16 + ((lane >> 4) * 4) + r4;
      const int bb = row >> 11, nn = row & 2047;
      #pragma unroll
      for (int n = 0; n < 4; n++){
        const int col = c0 + wc*64 + n*16 + (lane & 15);
        const int which = col >> 10;
        const int h = (col >> 6) & 15, d = col & 63;
        float* dst = (which == 0) ? qw : ((which == 1) ? kw : vw);
        dst[(((size_t)(bb*HEADS + h))*NTOT + (size_t)(nn + n_off))*DH + d] = acc[m][n][r4];
      }
    }
  }
}

// ---------------- K2: in-place mh_rmsnorm + RoPE on q,k ----------------
__global__ __launch_bounds__(256) void normrope_kernel(
    float* __restrict__ qw, float* __restrict__ kw,
    const float* __restrict__ gqx, const float* __restrict__ gkx,
    const float* __restrict__ gqa, const float* __restrict__ gka)
{
  const int tid = blockIdx.x * 256 + threadIdx.x;   // 0..262143
  const int t = tid >> 17;                          // 0=q, 1=k
  const int r = tid & 131071;                       // (b*16+h)*4096 + n
  const int n = r & 4095;
  const int h = (r >> 12) & 15;
  float* base = (t == 0 ? qw : kw) + (size_t)r * DH;
  const float* g = (t == 0) ? (n < NA ? gqa : gqx) : (n < NA ? gka : gkx);
  g += h * DH;
  float v[DH];
  #pragma unroll
  for (int i = 0; i < 16; i++){
    float4 f = ((const float4*)base)[i];
    v[4*i] = f.x; v[4*i+1] = f.y; v[4*i+2] = f.z; v[4*i+3] = f.w;
  }
  float ss = 0.f;
  #pragma unroll
  for (int d = 0; d < DH; d++) ss += v[d]*v[d];
  const float sc = 8.0f / fmaxf(sqrtf(ss), 1e-12f);
  #pragma unroll
  for (int d = 0; d < DH; d++) v[d] = v[d] * sc * g[d];
  float o[DH];
  const float fn = (float)n;
  #pragma unroll
  for (int d = 0; d < 32; d++){
    const float invf = expf(-(float)d * 0.28782313662425572f);  // 10000^(-d/32)
    float sn, cs;
    sincosf(fn * invf, &sn, &cs);
    o[d]    = v[d]*cs    - v[d+32]*sn;
    o[d+32] = v[d+32]*cs + v[d]*sn;
  }
  #pragma unroll
  for (int i = 0; i < 16; i++){
    float4 f; f.x = o[4*i]; f.y = o[4*i+1]; f.z = o[4*i+2]; f.w = o[4*i+3];
    ((float4*)base)[i] = f;
  }
}

// ---------------- K3: per-segment G_s = sk^T v (64x64), zc_s = sum sk ----------------
__global__ __launch_bounds__(256,1) void segG_kernel(const float* __restrict__ kw,
                                                     const float* __restrict__ vw,
                                                     float* __restrict__ G, float* __restrict__ zc){
  __shared__ float sk[SEG][DH];
  __shared__ float sv[SEG][DH];
  const int blk = blockIdx.x;           // bh*16 + s
  const int tid = threadIdx.x;
  const size_t segoff = ((size_t)(blk >> 4) * NTOT + (size_t)(blk & 15) * SEG) * DH;
  for (int i = tid; i < SEG*DH/4; i += 256){
    float4 kk = ((const float4*)(kw + segoff))[i];
    float4 s4;
    s4.x = kk.x > 0.f ? kk.x + 1.f : __expf(kk.x);
    s4.y = kk.y > 0.f ? kk.y + 1.f : __expf(kk.y);
    s4.z = kk.z > 0.f ? kk.z + 1.f : __expf(kk.z);
    s4.w = kk.w > 0.f ? kk.w + 1.f : __expf(kk.w);
    ((float4*)sk)[i] = s4;
    ((float4*)sv)[i] = ((const float4*)(vw + segoff))[i];
  }
  __syncthreads();
  const int d = tid >> 2, e0 = (tid & 3) * 16;
  float acc[16];
  #pragma unroll
  for (int e = 0; e < 16; e++) acc[e] = 0.f;
  float z = 0.f;
  for (int l = 0; l < SEG; l++){
    const float skd = sk[l][d];
    z += skd;
    #pragma unroll
    for (int e = 0; e < 16; e++) acc[e] += skd * sv[l][e0 + e];
  }
  float* Gout = G + (size_t)blk * DH * DH;
  #pragma unroll
  for (int e = 0; e < 16; e++) Gout[d*DH + e0 + e] = acc[e];
  if ((tid & 3) == 0) zc[(size_t)blk * DH + d] = z;
}

// ---------------- K4: exclusive prefix over segments -> Mp, zp ----------------
__global__ __launch_bounds__(256) void prefix_kernel(const float* __restrict__ G,
                                                     const float* __restrict__ zc,
                                                     float* __restrict__ Mp, float* __restrict__ zp){
  const int bh = blockIdx.x, tid = threadIdx.x;
  float run[16];
  #pragma unroll
  for (int k = 0; k < 16; k++) run[k] = 0.f;
  for (int s = 0; s < NSEG; s++){
    const size_t base = ((size_t)bh * NSEG + s) * DH * DH;
    #pragma unroll
    for (int k = 0; k < 16; k++){
      Mp[base + tid + 256*k] = run[k];
      run[k] += G[base + tid + 256*k];
    }
  }
  if (tid < DH){
    float rz = 0.f;
    for (int s = 0; s < NSEG; s++){
      zp[((size_t)bh*NSEG + s)*DH + tid] = rz;
      rz += zc[((size_t)bh*NSEG + s)*DH + tid];
    }
  }
}

// ---------------- K5: MFMA flash-attention per segment + gated memory readout ----------------
// Block = (bh, s), 256 threads = 4 waves; wave w owns q-rows [w*64, w*64+64).
// S^T = K Q^T via mfma; P packed to bf16 via explicit shift/mask (no v_perm);
// den accumulated from the SAME truncated bf16 p used in PV.
__global__ __launch_bounds__(256,1) void attn_mfma_kernel(
    const float* __restrict__ qw, const float* __restrict__ kw,
    const unsigned short* __restrict__ vt, const float* __restrict__ Mp,
    const float* __restrict__ zp, const float* __restrict__ beta,
    float* __restrict__ out)
{
  __shared__ unsigned short Qs[256*72];    // [row][d], stride 72 bf16
  __shared__ unsigned short KSs[256*72];   // K, later SQ*g/denm
  __shared__ unsigned short Vts[64*264];   // [e][j], stride 264
  __shared__ unsigned short Ps[4*64*72];   // per-wave P [i][j]
  __shared__ unsigned short Mts[64*72];    // M^T [e][d]
  __shared__ float den_s[256];
  __shared__ float zsh[64];

  const int blk = blockIdx.x;
  const int s = blk & 15, bh = blk >> 4;
  const int h = bh & 15, b = bh >> 4;
  const int tid = threadIdx.x;
  const int w = tid >> 6, lane = tid & 63;
  const int li = lane & 15, lg = lane >> 4;
  const size_t segoff = ((size_t)bh * NTOT + (size_t)s * SEG) * DH;

  // ---- stage Q, K (f32->bf16 RTNE), Vt (bf16 copy), Mt (transposed), zsh ----
  #pragma unroll
  for (int it = 0; it < 16; it++){
    const int idx = tid + it*256;            // 4096 chunks of 4 f32
    const int row = idx >> 4, dc = idx & 15;
    float4 fq = *(const float4*)(qw + segoff + (size_t)row*64 + dc*4);
    float4 fk = *(const float4*)(kw + segoff + (size_t)row*64 + dc*4);
    uint2 pq, pk;
    pq.x = f2bf(fq.x) | ((unsigned)f2bf(fq.y) << 16);
    pq.y = f2bf(fq.z) | ((unsigned)f2bf(fq.w) << 16);
    pk.x = f2bf(fk.x) | ((unsigned)f2bf(fk.y) << 16);
    pk.y = f2bf(fk.z) | ((unsigned)f2bf(fk.w) << 16);
    *(uint2*)(Qs  + row*72 + dc*4) = pq;
    *(uint2*)(KSs + row*72 + dc*4) = pk;
  }
  #pragma unroll
  for (int it = 0; it < 8; it++){
    const int idx = tid + it*256;            // 2048 b128 chunks
    const int e = idx >> 5, jc = idx & 31;
    *(u32x4*)(Vts + e*264 + jc*8) =
      *(const u32x4*)(vt + (size_t)bh*DH*NTOT + (size_t)e*NTOT + s*SEG + jc*8);
  }
  #pragma unroll
  for (int it = 0; it < 16; it++){
    const int idx = tid + it*256;            // 4096 elems of Mp [d][e]
    const int d = idx >> 6, e = idx & 63;
    Mts[e*72 + d] = f2bf(Mp[(size_t)blk*4096 + d*64 + e]);
  }
  if (tid < 64) zsh[tid] = zp[(size_t)blk*64 + tid];
  __syncthreads();

  // ---- flash kv-loop (per wave, no barriers) ----
  f32x4 o_acc[4][4] = {};
  float denr[4] = {0.f, 0.f, 0.f, 0.f};
  const int qrow0 = w*64;
  bf16x8 qf[4][2];
  #pragma unroll
  for (int it = 0; it < 4; it++)
    #pragma unroll
    for (int kb = 0; kb < 2; kb++)
      qf[it][kb] = *(const bf16x8*)(Qs + (qrow0 + it*16 + li)*72 + kb*32 + lg*8);

  for (int c = 0; c <= w; c++){
    f32x4 st[4][4] = {};
    #pragma unroll
    for (int jt = 0; jt < 4; jt++){
      bf16x8 kf0 = *(const bf16x8*)(KSs + (c*64 + jt*16 + li)*72 + 0  + lg*8);
      bf16x8 kf1 = *(const bf16x8*)(KSs + (c*64 + jt*16 + li)*72 + 32 + lg*8);
      #pragma unroll
      for (int it = 0; it < 4; it++){
        st[jt][it] = __builtin_amdgcn_mfma_f32_16x16x32_bf16(kf0, qf[it][0], st[jt][it], 0, 0, 0);
        st[jt][it] = __builtin_amdgcn_mfma_f32_16x16x32_bf16(kf1, qf[it][1], st[jt][it], 0, 0, 0);
      }
    }
    // exp + causal mask; truncate to bf16 via explicit bit ops; den from truncated values
    const bool diag = (c == w);
    #pragma unroll
    for (int jt = 0; jt < 4; jt++){
      #pragma unroll
      for (int it = 0; it < 4; it++){
        f32x4 p = st[jt][it];
        unsigned pb[4];
        #pragma unroll
        for (int r = 0; r < 4; r++){
          float pe = __expf(p[r] * 0.125f);
          if (diag && (jt*16 + lg*4 + r > it*16 + li)) pe = 0.f;
          pb[r] = __builtin_bit_cast(unsigned, pe) & 0xFFFF0000u;   // bf16 truncation
          p[r] = __builtin_bit_cast(float, pb[r]);                  // value actually used in PV
        }
        denr[it] += (p[0] + p[1]) + (p[2] + p[3]);
        uint2 pkk;
        pkk.x = (pb[0] >> 16) | pb[1];
        pkk.y = (pb[2] >> 16) | pb[3];
        *(uint2*)(Ps + w*4608 + (it*16 + li)*72 + jt*16 + lg*4) = pkk;
      }
    }
    // PV accumulate
    bf16x8 pf[4][2];
    #pragma unroll
    for (int it = 0; it < 4; it++)
      #pragma unroll
      for (int kb = 0; kb < 2; kb++)
        pf[it][kb] = *(const bf16x8*)(Ps + w*4608 + (it*16 + li)*72 + kb*32 + lg*8);
    #pragma unroll
    for (int et = 0; et < 4; et++){
      bf16x8 vf0 = *(const bf16x8*)(Vts + (et*16 + li)*264 + c*64 + 0  + lg*8);
      bf16x8 vf1 = *(const bf16x8*)(Vts + (et*16 + li)*264 + c*64 + 32 + lg*8);
      #pragma unroll
      for (int it = 0; it < 4; it++){
        o_acc[it][et] = __builtin_amdgcn_mfma_f32_16x16x32_bf16(pf[it][0], vf0, o_acc[it][et], 0, 0, 0);
        o_acc[it][et] = __builtin_amdgcn_mfma_f32_16x16x32_bf16(pf[it][1], vf1, o_acc[it][et], 0, 0, 0);
      }
    }
  }

  // den: reduce across lane groups, publish
  #pragma unroll
  for (int it = 0; it < 4; it++){
    denr[it] += __shfl_xor(denr[it], 16, 64);
    denr[it] += __shfl_xor(denr[it], 32, 64);
  }
  if (lane < 16){
    #pragma unroll
    for (int it = 0; it < 4; it++) den_s[qrow0 + it*16 + lane] = denr[it];
  }
  const float gate = 1.f / (1.f + __expf(-beta[h]));
  __syncthreads();

  // ---- SQ pass (thread = row): sq = elu(q)+1, denm = sq.z; store sq*g/denm over K's LDS ----
  {
    const int i = tid;
    float sqv[64];
    float denm = 0.f;
    #pragma unroll
    for (int u = 0; u < 8; u++){
      bf16x8 qv = *(const bf16x8*)(Qs + i*72 + u*8);
      #pragma unroll
      for (int t2 = 0; t2 < 8; t2++){
        float x = __builtin_bit_cast(float, ((unsigned)(unsigned short)qv[t2]) << 16);
        float sq = x > 0.f ? x + 1.f : __expf(x);
        sqv[u*8 + t2] = sq;
        denm += sq * zsh[u*8 + t2];
      }
    }
    const float c2 = gate / (denm + 1e-6f);
    #pragma unroll
    for (int u = 0; u < 16; u++){
      uint2 pw;
      pw.x = f2bf(sqv[u*4]*c2)   | ((unsigned)f2bf(sqv[u*4+1]*c2) << 16);
      pw.y = f2bf(sqv[u*4+2]*c2) | ((unsigned)f2bf(sqv[u*4+3]*c2) << 16);
      *(uint2*)(KSs + i*72 + u*4) = pw;
    }
  }
  __syncthreads();

  // ---- scale local by (1-gate)/den, add memory term via MFMA ----
  #pragma unroll
  for (int it = 0; it < 4; it++){
    #pragma unroll
    for (int r = 0; r < 4; r++){
      const float c1 = (1.f - gate) / den_s[qrow0 + it*16 + lg*4 + r];
      #pragma unroll
      for (int et = 0; et < 4; et++) o_acc[it][et][r] *= c1;
    }
  }
  #pragma unroll
  for (int kb = 0; kb < 2; kb++){
    bf16x8 mf[4];
    #pragma unroll
    for (int et = 0; et < 4; et++)
      mf[et] = *(const bf16x8*)(Mts + (et*16 + li)*72 + kb*32 + lg*8);
    #pragma unroll
    for (int it = 0; it < 4; it++){
      bf16x8 sf = *(const bf16x8*)(KSs + (qrow0 + it*16 + li)*72 + kb*32 + lg*8);
      #pragma unroll
      for (int et = 0; et < 4; et++)
        o_acc[it][et] = __builtin_amdgcn_mfma_f32_16x16x32_bf16(sf, mf[et], o_acc[it][et], 0, 0, 0);
    }
  }

  // ---- epilogue: f32 out, out_x chunk 0, out_a chunk 1 ----
  #pragma unroll
  for (int it = 0; it < 4; it++){
    #pragma unroll
    for (int r = 0; r < 4; r++){
      const int n_g = s*SEG + qrow0 + it*16 + lg*4 + r;
      size_t o;
      if (n_g >= NA) o = ((size_t)b * NX + (size_t)(n_g - NA)) * 1024 + h * 64;
      else           o = 4194304u + ((size_t)b * NA + (size_t)n_g) * 1024 + h * 64;
      #pragma unroll
      for (int et = 0; et < 4; et++)
        out[o + et*16 + li] = o_acc[it][et][r];
    }
  }
}

extern "C" void kernel_launch(void* const* d_in, const int* in_sizes, int n_in,
                              void* d_out, int out_size, void* d_ws, size_t ws_size,
                              hipStream_t stream)
{
  (void)ws_size;
  const int expect[9] = {4194304, 4194304, 3145728, 3145728, 1024, 1024, 1024, 1024, 16};
  bool ok = (n_in == 9);
  if (ok) for (int i = 0; i < 9; i++) if (in_sizes[i] != expect[i]) { ok = false; break; }
  float* out = (float*)d_out;
  if (!ok){
    zero_kernel<<<dim3((out_size + 255)/256), dim3(256), 0, stream>>>(out, out_size);
    return;
  }

  const float* x    = (const float*)d_in[0];
  const float* a    = (const float*)d_in[1];
  const float* wx   = (const float*)d_in[2];
  const float* wa   = (const float*)d_in[3];
  const float* gqx  = (const float*)d_in[4];
  const float* gkx  = (const float*)d_in[5];
  const float* gqa  = (const float*)d_in[6];
  const float* gka  = (const float*)d_in[7];
  const float* beta = (const float*)d_in[8];

  char* wsb = (char*)d_ws;
  float* qw = (float*)wsb;                                   // 33,554,432 B
  float* kw = qw + 8388608;                                  // 33,554,432 B
  float* vw = kw + 8388608;                                  // 33,554,432 B
  unsigned short* Xb  = (unsigned short*)(wsb + 100663296);  //  8,388,608 B
  unsigned short* Ab  = Xb + 4194304;                        //  8,388,608 B
  unsigned short* WTx = Ab + 4194304;                        //  6,291,456 B
  unsigned short* WTa = WTx + 3145728;                       //  6,291,456 B
  unsigned short* vtb = Xb;                                  // 16,777,216 B (reuses Xb+Ab after GEMMs)
  float* G   = (float*)(wsb + 130023424);                    //  8,388,608 B
  float* Mp  = G + 2097152;                                  //  8,388,608 B
  float* zc  = Mp + 2097152;                                 //    131,072 B
  float* zpb = zc + 32768;                                   //    131,072 B  (total ~147 MB)

  cvt_kernel<<<dim3(4096), dim3(256), 0, stream>>>(x, Xb, 1048576);
  cvt_kernel<<<dim3(4096), dim3(256), 0, stream>>>(a, Ab, 1048576);
  wtr_kernel<<<dim3(96,32), dim3(32,8), 0, stream>>>(wx, WTx);
  wtr_kernel<<<dim3(96,32), dim3(32,8), 0, stream>>>(wa, WTa);
  // a tokens occupy concatenated positions [0,2048); x tokens [2048,4096)
  gemm_qkv_kernel<<<dim3(24,32), dim3(256), 0, stream>>>(Xb, WTx, qw, kw, vw, 2048);
  gemm_qkv_kernel<<<dim3(24,32), dim3(256), 0, stream>>>(Ab, WTa, qw, kw, vw, 0);
  vtr_kernel<<<dim3(128, 2, 32), dim3(32,8), 0, stream>>>(vw, vtb);   // after GEMMs (reuses Xb/Ab)
  normrope_kernel<<<dim3(1024), dim3(256), 0, stream>>>(qw, kw, gqx, gkx, gqa, gka);
  segG_kernel<<<dim3(512), dim3(256), 0, stream>>>(kw, vw, G, zc);
  prefix_kernel<<<dim3(32), dim3(256), 0, stream>>>(G, zc, Mp, zpb);
  attn_mfma_kernel<<<dim3(512), dim3(256), 0, stream>>>(qw, kw, vtb, Mp, zpb, beta, out);
}

// Round 14
// 248.073 us; speedup vs baseline: 1.8737x; 1.0774x over previous
//
#include <hip/hip_runtime.h>

#define HEADS 16
#define DH    64
#define NA    2048
#define NX    2048
#define NTOT  4096
#define DIMK  1024
#define NQKV  3072
#define SEG   256
#define NSEG  16

typedef float          f32x4  __attribute__((ext_vector_type(4)));
typedef short          bf16x8 __attribute__((ext_vector_type(8)));
typedef unsigned int   u32x4  __attribute__((ext_vector_type(4)));

// f32 -> bf16 bits, round-to-nearest-even (finite inputs)
__device__ __forceinline__ unsigned short f2bf(float f){
  unsigned int u = __builtin_bit_cast(unsigned int, f);
  unsigned int r = 0x7fffu + ((u >> 16) & 1u);
  return (unsigned short)((u + r) >> 16);
}

__global__ __launch_bounds__(256) void zero_kernel(float* __restrict__ out, int n){
  int i = blockIdx.x * 256 + threadIdx.x;
  if (i < n) out[i] = 0.f;
}

// ---------------- K0a: f32 -> bf16 elementwise ----------------
__global__ __launch_bounds__(256) void cvt_kernel(const float* __restrict__ src,
                                                  unsigned short* __restrict__ dst, int n4){
  int i = blockIdx.x * 256 + threadIdx.x;
  if (i >= n4) return;
  float4 v = ((const float4*)src)[i];
  ushort4 o;
  o.x = f2bf(v.x); o.y = f2bf(v.y); o.z = f2bf(v.z); o.w = f2bf(v.w);
  ((ushort4*)dst)[i] = o;
}

// ---------------- K0b: W [DIMK][NQKV] f32 -> WT [NQKV][DIMK] bf16 ----------------
__global__ __launch_bounds__(256) void wtr_kernel(const float* __restrict__ W,
                                                  unsigned short* __restrict__ WT){
  __shared__ float tile[32][33];
  int c0 = blockIdx.x * 32, k0 = blockIdx.y * 32;
  int tx = threadIdx.x, ty = threadIdx.y;
  #pragma unroll
  for (int i = 0; i < 32; i += 8) tile[ty+i][tx] = W[(size_t)(k0+ty+i)*NQKV + c0 + tx];
  __syncthreads();
  #pragma unroll
  for (int i = 0; i < 32; i += 8) WT[(size_t)(c0+ty+i)*DIMK + k0 + tx] = f2bf(tile[tx][ty+i]);
}

// ---------------- K0c: vw (b,h,n,d) f32 -> vt (b,h,d,n) bf16 ----------------
__global__ __launch_bounds__(256) void vtr_kernel(const float* __restrict__ vw,
                                                  unsigned short* __restrict__ vt){
  __shared__ float tile[32][33];
  const int nt = blockIdx.x, dt = blockIdx.y, bh = blockIdx.z;
  const int tx = threadIdx.x, ty = threadIdx.y;
  const size_t base = (size_t)bh * NTOT * DH;
  #pragma unroll
  for (int i = 0; i < 32; i += 8)
    tile[ty+i][tx] = vw[base + (size_t)(nt*32 + ty+i)*DH + dt*32 + tx];
  __syncthreads();
  #pragma unroll
  for (int i = 0; i < 32; i += 8)
    vt[(size_t)bh*DH*NTOT + (size_t)(dt*32 + ty+i)*NTOT + nt*32 + tx] = f2bf(tile[tx][ty+i]);
}

// ---------------- K0d: exact RoPE cos/sin table [n][d][2], 131072 entries ----------------
__global__ __launch_bounds__(256) void rope_tab_kernel(float* __restrict__ tab){
  const int idx = blockIdx.x * 256 + threadIdx.x;   // < 131072
  const int n = idx >> 5, d = idx & 31;
  const float ang = (float)n * expf(-(float)d * 0.28782313662425572f);  // n * 10000^(-d/32)
  float sn, cs;
  sincosf(ang, &sn, &cs);
  float2 p; p.x = cs; p.y = sn;
  ((float2*)tab)[idx] = p;
}

// ---------------- K1: bf16 MFMA GEMM, scatter into q/k/v (b,h,n,d) f32 ----------------
__global__ __launch_bounds__(256,2) void gemm_qkv_kernel(
    const unsigned short* __restrict__ Xb, const unsigned short* __restrict__ WT,
    float* __restrict__ qw, float* __restrict__ kw, float* __restrict__ vw, const int n_off)
{
  __shared__ __align__(16) unsigned short As[128*32];
  __shared__ __align__(16) unsigned short Bs[128*32];
  const int tid  = threadIdx.x;
  const int lane = tid & 63, w = tid >> 6;
  const int wr = w >> 1, wc = w & 1;
  const int m0 = blockIdx.y * 128, c0 = blockIdx.x * 128;

  f32x4 acc[4][4] = {};

  for (int k0 = 0; k0 < DIMK; k0 += 32){
    __syncthreads();
    #pragma unroll
    for (int cc = 0; cc < 2; cc++){
      const int c = tid*2 + cc;
      const int row = c >> 2, slot = c & 3;
      const int gs = slot ^ (row & 3);
      *(u32x4*)(&As[row*32 + slot*8]) = *(const u32x4*)(Xb + (size_t)(m0+row)*DIMK + k0 + gs*8);
      *(u32x4*)(&Bs[row*32 + slot*8]) = *(const u32x4*)(WT + (size_t)(c0+row)*DIMK + k0 + gs*8);
    }
    __syncthreads();
    bf16x8 af[4], bf[4];
    const int kc = lane >> 4;
    #pragma unroll
    for (int m = 0; m < 4; m++){
      const int r = wr*64 + m*16 + (lane & 15);
      af[m] = *(const bf16x8*)(&As[r*32 + ((kc ^ (r & 3)) * 8)]);
    }
    #pragma unroll
    for (int n = 0; n < 4; n++){
      const int r = wc*64 + n*16 + (lane & 15);
      bf[n] = *(const bf16x8*)(&Bs[r*32 + ((kc ^ (r & 3)) * 8)]);
    }
    #pragma unroll
    for (int m = 0; m < 4; m++)
      #pragma unroll
      for (int n = 0; n < 4; n++)
        acc[m][n] = __builtin_amdgcn_mfma_f32_16x16x32_bf16(af[m], bf[n], acc[m][n], 0, 0, 0);
  }

  #pragma unroll
  for (int m = 0; m < 4; m++){
    #pragma unroll
    for (int r4 = 0; r4 < 4; r4++){
      const int row = m0 + wr*64 + m*16 + ((lane >> 4) * 4) + r4;
      const int bb = row >> 11, nn = row & 2047;
      #pragma unroll
      for (int n = 0; n < 4; n++){
        const int col = c0 + wc*64 + n*16 + (lane & 15);
        const int which = col >> 10;
        const int h = (col >> 6) & 15, d = col & 63;
        float* dst = (which == 0) ? qw : ((which == 1) ? kw : vw);
        dst[(((size_t)(bb*HEADS + h))*NTOT + (size_t)(nn + n_off))*DH + d] = acc[m][n][r4];
      }
    }
  }
}

// ---------------- K2: in-place mh_rmsnorm + RoPE on q,k (table-based, no trig) ----------------
__global__ __launch_bounds__(256) void normrope_kernel(
    float* __restrict__ qw, float* __restrict__ kw,
    const float* __restrict__ gqx, const float* __restrict__ gkx,
    const float* __restrict__ gqa, const float* __restrict__ gka,
    const float* __restrict__ tab)
{
  const int tid = blockIdx.x * 256 + threadIdx.x;   // 0..262143
  const int t = tid >> 17;                          // 0=q, 1=k
  const int r = tid & 131071;                       // (b*16+h)*4096 + n
  const int n = r & 4095;
  const int h = (r >> 12) & 15;
  float* base = (t == 0 ? qw : kw) + (size_t)r * DH;
  const float* g = (t == 0) ? (n < NA ? gqa : gqx) : (n < NA ? gka : gkx);
  g += h * DH;
  float v[DH];
  #pragma unroll
  for (int i = 0; i < 16; i++){
    float4 f = ((const float4*)base)[i];
    v[4*i] = f.x; v[4*i+1] = f.y; v[4*i+2] = f.z; v[4*i+3] = f.w;
  }
  float ss = 0.f;
  #pragma unroll
  for (int d = 0; d < DH; d++) ss += v[d]*v[d];
  const float sc = 8.0f / fmaxf(sqrtf(ss), 1e-12f);
  #pragma unroll
  for (int d = 0; d < DH; d++) v[d] = v[d] * sc * g[d];
  // RoPE via precomputed exact table: trow[2d]=cos, trow[2d+1]=sin
  const float* trow = tab + (size_t)n * 64;
  float o[DH];
  #pragma unroll
  for (int i = 0; i < 16; i++){
    float4 cs2 = ((const float4*)trow)[i];   // (cos,sin,cos,sin) for d = 2i, 2i+1
    const int d0 = 2*i, d1 = 2*i + 1;
    o[d0]      = v[d0]*cs2.x      - v[d0+32]*cs2.y;
    o[d0+32]   = v[d0+32]*cs2.x   + v[d0]*cs2.y;
    o[d1]      = v[d1]*cs2.z      - v[d1+32]*cs2.w;
    o[d1+32]   = v[d1+32]*cs2.z   + v[d1]*cs2.w;
  }
  #pragma unroll
  for (int i = 0; i < 16; i++){
    float4 f; f.x = o[4*i]; f.y = o[4*i+1]; f.z = o[4*i+2]; f.w = o[4*i+3];
    ((float4*)base)[i] = f;
  }
}

// ---------------- K3: per-segment G_s = sk^T v (64x64), zc_s = sum sk ----------------
__global__ __launch_bounds__(256,1) void segG_kernel(const float* __restrict__ kw,
                                                     const float* __restrict__ vw,
                                                     float* __restrict__ G, float* __restrict__ zc){
  __shared__ float sk[SEG][DH];
  __shared__ float sv[SEG][DH];
  const int blk = blockIdx.x;           // bh*16 + s
  const int tid = threadIdx.x;
  const size_t segoff = ((size_t)(blk >> 4) * NTOT + (size_t)(blk & 15) * SEG) * DH;
  for (int i = tid; i < SEG*DH/4; i += 256){
    float4 kk = ((const float4*)(kw + segoff))[i];
    float4 s4;
    s4.x = kk.x > 0.f ? kk.x + 1.f : __expf(kk.x);
    s4.y = kk.y > 0.f ? kk.y + 1.f : __expf(kk.y);
    s4.z = kk.z > 0.f ? kk.z + 1.f : __expf(kk.z);
    s4.w = kk.w > 0.f ? kk.w + 1.f : __expf(kk.w);
    ((float4*)sk)[i] = s4;
    ((float4*)sv)[i] = ((const float4*)(vw + segoff))[i];
  }
  __syncthreads();
  const int d = tid >> 2, e0 = (tid & 3) * 16;
  float acc[16];
  #pragma unroll
  for (int e = 0; e < 16; e++) acc[e] = 0.f;
  float z = 0.f;
  for (int l = 0; l < SEG; l++){
    const float skd = sk[l][d];
    z += skd;
    #pragma unroll
    for (int e = 0; e < 16; e++) acc[e] += skd * sv[l][e0 + e];
  }
  float* Gout = G + (size_t)blk * DH * DH;
  #pragma unroll
  for (int e = 0; e < 16; e++) Gout[d*DH + e0 + e] = acc[e];
  if ((tid & 3) == 0) zc[(size_t)blk * DH + d] = z;
}

// ---------------- K4: exclusive prefix over segments -> Mp, zp ----------------
__global__ __launch_bounds__(256) void prefix_kernel(const float* __restrict__ G,
                                                     const float* __restrict__ zc,
                                                     float* __restrict__ Mp, float* __restrict__ zp){
  const int bh = blockIdx.x, tid = threadIdx.x;
  float run[16];
  #pragma unroll
  for (int k = 0; k < 16; k++) run[k] = 0.f;
  for (int s = 0; s < NSEG; s++){
    const size_t base = ((size_t)bh * NSEG + s) * DH * DH;
    #pragma unroll
    for (int k = 0; k < 16; k++){
      Mp[base + tid + 256*k] = run[k];
      run[k] += G[base + tid + 256*k];
    }
  }
  if (tid < DH){
    float rz = 0.f;
    for (int s = 0; s < NSEG; s++){
      zp[((size_t)bh*NSEG + s)*DH + tid] = rz;
      rz += zc[((size_t)bh*NSEG + s)*DH + tid];
    }
  }
}

// ---------------- K5: MFMA flash-attention per segment + gated memory readout ----------------
__global__ __launch_bounds__(256,1) void attn_mfma_kernel(
    const float* __restrict__ qw, const float* __restrict__ kw,
    const unsigned short* __restrict__ vt, const float* __restrict__ Mp,
    const float* __restrict__ zp, const float* __restrict__ beta,
    float* __restrict__ out)
{
  __shared__ unsigned short Qs[256*72];    // [row][d], stride 72 bf16
  __shared__ unsigned short KSs[256*72];   // K, later SQ*g/denm
  __shared__ unsigned short Vts[64*264];   // [e][j], stride 264
  __shared__ unsigned short Ps[4*64*72];   // per-wave P [i][j]
  __shared__ unsigned short Mts[64*72];    // M^T [e][d]
  __shared__ float den_s[256];
  __shared__ float zsh[64];

  const int blk = blockIdx.x;
  const int s = blk & 15, bh = blk >> 4;
  const int h = bh & 15, b = bh >> 4;
  const int tid = threadIdx.x;
  const int w = tid >> 6, lane = tid & 63;
  const int li = lane & 15, lg = lane >> 4;
  const size_t segoff = ((size_t)bh * NTOT + (size_t)s * SEG) * DH;

  #pragma unroll
  for (int it = 0; it < 16; it++){
    const int idx = tid + it*256;            // 4096 chunks of 4 f32
    const int row = idx >> 4, dc = idx & 15;
    float4 fq = *(const float4*)(qw + segoff + (size_t)row*64 + dc*4);
    float4 fk = *(const float4*)(kw + segoff + (size_t)row*64 + dc*4);
    uint2 pq, pk;
    pq.x = f2bf(fq.x) | ((unsigned)f2bf(fq.y) << 16);
    pq.y = f2bf(fq.z) | ((unsigned)f2bf(fq.w) << 16);
    pk.x = f2bf(fk.x) | ((unsigned)f2bf(fk.y) << 16);
    pk.y = f2bf(fk.z) | ((unsigned)f2bf(fk.w) << 16);
    *(uint2*)(Qs  + row*72 + dc*4) = pq;
    *(uint2*)(KSs + row*72 + dc*4) = pk;
  }
  #pragma unroll
  for (int it = 0; it < 8; it++){
    const int idx = tid + it*256;            // 2048 b128 chunks
    const int e = idx >> 5, jc = idx & 31;
    *(u32x4*)(Vts + e*264 + jc*8) =
      *(const u32x4*)(vt + (size_t)bh*DH*NTOT + (size_t)e*NTOT + s*SEG + jc*8);
  }
  #pragma unroll
  for (int it = 0; it < 16; it++){
    const int idx = tid + it*256;            // 4096 elems of Mp [d][e]
    const int d = idx >> 6, e = idx & 63;
    Mts[e*72 + d] = f2bf(Mp[(size_t)blk*4096 + d*64 + e]);
  }
  if (tid < 64) zsh[tid] = zp[(size_t)blk*64 + tid];
  __syncthreads();

  f32x4 o_acc[4][4] = {};
  float denr[4] = {0.f, 0.f, 0.f, 0.f};
  const int qrow0 = w*64;
  bf16x8 qf[4][2];
  #pragma unroll
  for (int it = 0; it < 4; it++)
    #pragma unroll
    for (int kb = 0; kb < 2; kb++)
      qf[it][kb] = *(const bf16x8*)(Qs + (qrow0 + it*16 + li)*72 + kb*32 + lg*8);

  for (int c = 0; c <= w; c++){
    f32x4 st[4][4] = {};
    #pragma unroll
    for (int jt = 0; jt < 4; jt++){
      bf16x8 kf0 = *(const bf16x8*)(KSs + (c*64 + jt*16 + li)*72 + 0  + lg*8);
      bf16x8 kf1 = *(const bf16x8*)(KSs + (c*64 + jt*16 + li)*72 + 32 + lg*8);
      #pragma unroll
      for (int it = 0; it < 4; it++){
        st[jt][it] = __builtin_amdgcn_mfma_f32_16x16x32_bf16(kf0, qf[it][0], st[jt][it], 0, 0, 0);
        st[jt][it] = __builtin_amdgcn_mfma_f32_16x16x32_bf16(kf1, qf[it][1], st[jt][it], 0, 0, 0);
      }
    }
    const bool diag = (c == w);
    #pragma unroll
    for (int jt = 0; jt < 4; jt++){
      #pragma unroll
      for (int it = 0; it < 4; it++){
        f32x4 p = st[jt][it];
        unsigned pb[4];
        #pragma unroll
        for (int r = 0; r < 4; r++){
          float pe = __expf(p[r] * 0.125f);
          if (diag && (jt*16 + lg*4 + r > it*16 + li)) pe = 0.f;
          pb[r] = __builtin_bit_cast(unsigned, pe) & 0xFFFF0000u;   // bf16 truncation
          p[r] = __builtin_bit_cast(float, pb[r]);                  // value actually used in PV
        }
        denr[it] += (p[0] + p[1]) + (p[2] + p[3]);
        uint2 pkk;
        pkk.x = (pb[0] >> 16) | pb[1];
        pkk.y = (pb[2] >> 16) | pb[3];
        *(uint2*)(Ps + w*4608 + (it*16 + li)*72 + jt*16 + lg*4) = pkk;
      }
    }
    bf16x8 pf[4][2];
    #pragma unroll
    for (int it = 0; it < 4; it++)
      #pragma unroll
      for (int kb = 0; kb < 2; kb++)
        pf[it][kb] = *(const bf16x8*)(Ps + w*4608 + (it*16 + li)*72 + kb*32 + lg*8);
    #pragma unroll
    for (int et = 0; et < 4; et++){
      bf16x8 vf0 = *(const bf16x8*)(Vts + (et*16 + li)*264 + c*64 + 0  + lg*8);
      bf16x8 vf1 = *(const bf16x8*)(Vts + (et*16 + li)*264 + c*64 + 32 + lg*8);
      #pragma unroll
      for (int it = 0; it < 4; it++){
        o_acc[it][et] = __builtin_amdgcn_mfma_f32_16x16x32_bf16(pf[it][0], vf0, o_acc[it][et], 0, 0, 0);
        o_acc[it][et] = __builtin_amdgcn_mfma_f32_16x16x32_bf16(pf[it][1], vf1, o_acc[it][et], 0, 0, 0);
      }
    }
  }

  #pragma unroll
  for (int it = 0; it < 4; it++){
    denr[it] += __shfl_xor(denr[it], 16, 64);
    denr[it] += __shfl_xor(denr[it], 32, 64);
  }
  if (lane < 16){
    #pragma unroll
    for (int it = 0; it < 4; it++) den_s[qrow0 + it*16 + lane] = denr[it];
  }
  const float gate = 1.f / (1.f + __expf(-beta[h]));
  __syncthreads();

  {
    const int i = tid;
    float sqv[64];
    float denm = 0.f;
    #pragma unroll
    for (int u = 0; u < 8; u++){
      bf16x8 qv = *(const bf16x8*)(Qs + i*72 + u*8);
      #pragma unroll
      for (int t2 = 0; t2 < 8; t2++){
        float x = __builtin_bit_cast(float, ((unsigned)(unsigned short)qv[t2]) << 16);
        float sq = x > 0.f ? x + 1.f : __expf(x);
        sqv[u*8 + t2] = sq;
        denm += sq * zsh[u*8 + t2];
      }
    }
    const float c2 = gate / (denm + 1e-6f);
    #pragma unroll
    for (int u = 0; u < 16; u++){
      uint2 pw;
      pw.x = f2bf(sqv[u*4]*c2)   | ((unsigned)f2bf(sqv[u*4+1]*c2) << 16);
      pw.y = f2bf(sqv[u*4+2]*c2) | ((unsigned)f2bf(sqv[u*4+3]*c2) << 16);
      *(uint2*)(KSs + i*72 + u*4) = pw;
    }
  }
  __syncthreads();

  #pragma unroll
  for (int it = 0; it < 4; it++){
    #pragma unroll
    for (int r = 0; r < 4; r++){
      const float c1 = (1.f - gate) / den_s[qrow0 + it*16 + lg*4 + r];
      #pragma unroll
      for (int et = 0; et < 4; et++) o_acc[it][et][r] *= c1;
    }
  }
  #pragma unroll
  for (int kb = 0; kb < 2; kb++){
    bf16x8 mf[4];
    #pragma unroll
    for (int et = 0; et < 4; et++)
      mf[et] = *(const bf16x8*)(Mts + (et*16 + li)*72 + kb*32 + lg*8);
    #pragma unroll
    for (int it = 0; it < 4; it++){
      bf16x8 sf = *(const bf16x8*)(KSs + (qrow0 + it*16 + li)*72 + kb*32 + lg*8);
      #pragma unroll
      for (int et = 0; et < 4; et++)
        o_acc[it][et] = __builtin_amdgcn_mfma_f32_16x16x32_bf16(sf, mf[et], o_acc[it][et], 0, 0, 0);
    }
  }

  #pragma unroll
  for (int it = 0; it < 4; it++){
    #pragma unroll
    for (int r = 0; r < 4; r++){
      const int n_g = s*SEG + qrow0 + it*16 + lg*4 + r;
      size_t o;
      if (n_g >= NA) o = ((size_t)b * NX + (size_t)(n_g - NA)) * 1024 + h * 64;
      else           o = 4194304u + ((size_t)b * NA + (size_t)n_g) * 1024 + h * 64;
      #pragma unroll
      for (int et = 0; et < 4; et++)
        out[o + et*16 + li] = o_acc[it][et][r];
    }
  }
}

extern "C" void kernel_launch(void* const* d_in, const int* in_sizes, int n_in,
                              void* d_out, int out_size, void* d_ws, size_t ws_size,
                              hipStream_t stream)
{
  (void)ws_size;
  const int expect[9] = {4194304, 4194304, 3145728, 3145728, 1024, 1024, 1024, 1024, 16};
  bool ok = (n_in == 9);
  if (ok) for (int i = 0; i < 9; i++) if (in_sizes[i] != expect[i]) { ok = false; break; }
  float* out = (float*)d_out;
  if (!ok){
    zero_kernel<<<dim3((out_size + 255)/256), dim3(256), 0, stream>>>(out, out_size);
    return;
  }

  const float* x    = (const float*)d_in[0];
  const float* a    = (const float*)d_in[1];
  const float* wx   = (const float*)d_in[2];
  const float* wa   = (const float*)d_in[3];
  const float* gqx  = (const float*)d_in[4];
  const float* gkx  = (const float*)d_in[5];
  const float* gqa  = (const float*)d_in[6];
  const float* gka  = (const float*)d_in[7];
  const float* beta = (const float*)d_in[8];

  char* wsb = (char*)d_ws;
  float* qw = (float*)wsb;                                   // 33,554,432 B
  float* kw = qw + 8388608;                                  // 33,554,432 B
  float* vw = kw + 8388608;                                  // 33,554,432 B
  unsigned short* Xb  = (unsigned short*)(wsb + 100663296);  //  8,388,608 B
  unsigned short* Ab  = Xb + 4194304;                        //  8,388,608 B
  unsigned short* WTx = Ab + 4194304;                        //  6,291,456 B
  unsigned short* WTa = WTx + 3145728;                       //  6,291,456 B
  unsigned short* vtb = Xb;                                  // 16,777,216 B (reuses Xb+Ab after GEMMs)
  float* ropetab = (float*)WTx;                              //  1,048,576 B (reuses WTx after GEMMs)
  float* G   = (float*)(wsb + 130023424);                    //  8,388,608 B
  float* Mp  = G + 2097152;                                  //  8,388,608 B
  float* zc  = Mp + 2097152;                                 //    131,072 B
  float* zpb = zc + 32768;                                   //    131,072 B  (total ~147 MB)

  cvt_kernel<<<dim3(4096), dim3(256), 0, stream>>>(x, Xb, 1048576);
  cvt_kernel<<<dim3(4096), dim3(256), 0, stream>>>(a, Ab, 1048576);
  wtr_kernel<<<dim3(96,32), dim3(32,8), 0, stream>>>(wx, WTx);
  wtr_kernel<<<dim3(96,32), dim3(32,8), 0, stream>>>(wa, WTa);
  // a tokens occupy concatenated positions [0,2048); x tokens [2048,4096)
  gemm_qkv_kernel<<<dim3(24,32), dim3(256), 0, stream>>>(Xb, WTx, qw, kw, vw, 2048);
  gemm_qkv_kernel<<<dim3(24,32), dim3(256), 0, stream>>>(Ab, WTa, qw, kw, vw, 0);
  vtr_kernel<<<dim3(128, 2, 32), dim3(32,8), 0, stream>>>(vw, vtb);        // after GEMMs (reuses Xb/Ab)
  rope_tab_kernel<<<dim3(512), dim3(256), 0, stream>>>(ropetab);           // after GEMMs (reuses WTx)
  normrope_kernel<<<dim3(1024), dim3(256), 0, stream>>>(qw, kw, gqx, gkx, gqa, gka, ropetab);
  segG_kernel<<<dim3(512), dim3(256), 0, stream>>>(kw, vw, G, zc);
  prefix_kernel<<<dim3(32), dim3(256), 0, stream>>>(G, zc, Mp, zpb);
  attn_mfma_kernel<<<dim3(512), dim3(256), 0, stream>>>(qw, kw, vtb, Mp, zpb, beta, out);
}

// Round 15
// 241.344 us; speedup vs baseline: 1.9259x; 1.0279x over previous
//
#include <hip/hip_runtime.h>

#define HEADS 16
#define DH    64
#define NA    2048
#define NX    2048
#define NTOT  4096
#define DIMK  1024
#define NQKV  3072
#define SEG   256
#define NSEG  16

typedef float          f32x4  __attribute__((ext_vector_type(4)));
typedef short          bf16x8 __attribute__((ext_vector_type(8)));
typedef unsigned int   u32x4  __attribute__((ext_vector_type(4)));

// f32 -> bf16 bits, round-to-nearest-even (finite inputs)
__device__ __forceinline__ unsigned short f2bf(float f){
  unsigned int u = __builtin_bit_cast(unsigned int, f);
  unsigned int r = 0x7fffu + ((u >> 16) & 1u);
  return (unsigned short)((u + r) >> 16);
}

__global__ __launch_bounds__(256) void zero_kernel(float* __restrict__ out, int n){
  int i = blockIdx.x * 256 + threadIdx.x;
  if (i < n) out[i] = 0.f;
}

// ---------------- K0a: f32 -> bf16 elementwise ----------------
__global__ __launch_bounds__(256) void cvt_kernel(const float* __restrict__ src,
                                                  unsigned short* __restrict__ dst, int n4){
  int i = blockIdx.x * 256 + threadIdx.x;
  if (i >= n4) return;
  float4 v = ((const float4*)src)[i];
  ushort4 o;
  o.x = f2bf(v.x); o.y = f2bf(v.y); o.z = f2bf(v.z); o.w = f2bf(v.w);
  ((ushort4*)dst)[i] = o;
}

// ---------------- K0b: W [DIMK][NQKV] f32 -> WT [NQKV][DIMK] bf16 ----------------
__global__ __launch_bounds__(256) void wtr_kernel(const float* __restrict__ W,
                                                  unsigned short* __restrict__ WT){
  __shared__ float tile[32][33];
  int c0 = blockIdx.x * 32, k0 = blockIdx.y * 32;
  int tx = threadIdx.x, ty = threadIdx.y;
  #pragma unroll
  for (int i = 0; i < 32; i += 8) tile[ty+i][tx] = W[(size_t)(k0+ty+i)*NQKV + c0 + tx];
  __syncthreads();
  #pragma unroll
  for (int i = 0; i < 32; i += 8) WT[(size_t)(c0+ty+i)*DIMK + k0 + tx] = f2bf(tile[tx][ty+i]);
}

// ---------------- K0c: vw (b,h,n,d) f32 -> vt (b,h,d,n) bf16 ----------------
__global__ __launch_bounds__(256) void vtr_kernel(const float* __restrict__ vw,
                                                  unsigned short* __restrict__ vt){
  __shared__ float tile[32][33];
  const int nt = blockIdx.x, dt = blockIdx.y, bh = blockIdx.z;
  const int tx = threadIdx.x, ty = threadIdx.y;
  const size_t base = (size_t)bh * NTOT * DH;
  #pragma unroll
  for (int i = 0; i < 32; i += 8)
    tile[ty+i][tx] = vw[base + (size_t)(nt*32 + ty+i)*DH + dt*32 + tx];
  __syncthreads();
  #pragma unroll
  for (int i = 0; i < 32; i += 8)
    vt[(size_t)bh*DH*NTOT + (size_t)(dt*32 + ty+i)*NTOT + nt*32 + tx] = f2bf(tile[tx][ty+i]);
}

// ---------------- K0d: exact RoPE cos/sin table [n][d][2], 131072 entries ----------------
__global__ __launch_bounds__(256) void rope_tab_kernel(float* __restrict__ tab){
  const int idx = blockIdx.x * 256 + threadIdx.x;   // < 131072
  const int n = idx >> 5, d = idx & 31;
  const float ang = (float)n * expf(-(float)d * 0.28782313662425572f);  // n * 10000^(-d/32)
  float sn, cs;
  sincosf(ang, &sn, &cs);
  float2 p; p.x = cs; p.y = sn;
  ((float2*)tab)[idx] = p;
}

// ---------------- K1: bf16 MFMA GEMM, scatter into q/k/v (b,h,n,d) f32 ----------------
__global__ __launch_bounds__(256,2) void gemm_qkv_kernel(
    const unsigned short* __restrict__ Xb, const unsigned short* __restrict__ WT,
    float* __restrict__ qw, float* __restrict__ kw, float* __restrict__ vw, const int n_off)
{
  __shared__ __align__(16) unsigned short As[128*32];
  __shared__ __align__(16) unsigned short Bs[128*32];
  const int tid  = threadIdx.x;
  const int lane = tid & 63, w = tid >> 6;
  const int wr = w >> 1, wc = w & 1;
  const int m0 = blockIdx.y * 128, c0 = blockIdx.x * 128;

  f32x4 acc[4][4] = {};

  for (int k0 = 0; k0 < DIMK; k0 += 32){
    __syncthreads();
    #pragma unroll
    for (int cc = 0; cc < 2; cc++){
      const int c = tid*2 + cc;
      const int row = c >> 2, slot = c & 3;
      const int gs = slot ^ (row & 3);
      *(u32x4*)(&As[row*32 + slot*8]) = *(const u32x4*)(Xb + (size_t)(m0+row)*DIMK + k0 + gs*8);
      *(u32x4*)(&Bs[row*32 + slot*8]) = *(const u32x4*)(WT + (size_t)(c0+row)*DIMK + k0 + gs*8);
    }
    __syncthreads();
    bf16x8 af[4], bf[4];
    const int kc = lane >> 4;
    #pragma unroll
    for (int m = 0; m < 4; m++){
      const int r = wr*64 + m*16 + (lane & 15);
      af[m] = *(const bf16x8*)(&As[r*32 + ((kc ^ (r & 3)) * 8)]);
    }
    #pragma unroll
    for (int n = 0; n < 4; n++){
      const int r = wc*64 + n*16 + (lane & 15);
      bf[n] = *(const bf16x8*)(&Bs[r*32 + ((kc ^ (r & 3)) * 8)]);
    }
    #pragma unroll
    for (int m = 0; m < 4; m++)
      #pragma unroll
      for (int n = 0; n < 4; n++)
        acc[m][n] = __builtin_amdgcn_mfma_f32_16x16x32_bf16(af[m], bf[n], acc[m][n], 0, 0, 0);
  }

  #pragma unroll
  for (int m = 0; m < 4; m++){
    #pragma unroll
    for (int r4 = 0; r4 < 4; r4++){
      const int row = m0 + wr*64 + m*16 + ((lane >> 4) * 4) + r4;
      const int bb = row >> 11, nn = row & 2047;
      #pragma unroll
      for (int n = 0; n < 4; n++){
        const int col = c0 + wc*64 + n*16 + (lane & 15);
        const int which = col >> 10;
        const int h = (col >> 6) & 15, d = col & 63;
        float* dst = (which == 0) ? qw : ((which == 1) ? kw : vw);
        dst[(((size_t)(bb*HEADS + h))*NTOT + (size_t)(nn + n_off))*DH + d] = acc[m][n][r4];
      }
    }
  }
}

// ---------------- K2: wave-per-row mh_rmsnorm + RoPE (coalesced, no arrays) ----------------
// Lane = dim d; 64 lanes = one (tensor,b,h,n) row. Table-based trig.
__global__ __launch_bounds__(256) void normrope_kernel(
    float* __restrict__ qw, float* __restrict__ kw,
    const float* __restrict__ gqx, const float* __restrict__ gkx,
    const float* __restrict__ gqa, const float* __restrict__ gka,
    const float* __restrict__ tab)
{
  const int gtid = blockIdx.x * 256 + threadIdx.x;
  const int R    = gtid >> 6;          // row 0..262143
  const int lane = gtid & 63;          // dim
  const int t    = R >> 17;            // 0=q, 1=k
  const int r    = R & 131071;         // (b*16+h)*4096 + n
  const int n    = r & 4095;
  const int h    = (r >> 12) & 15;
  float* base = (t == 0 ? qw : kw) + (size_t)r * DH;
  const float* g = (t == 0) ? (n < NA ? gqa : gqx) : (n < NA ? gka : gkx);

  const float val = base[lane];
  float ss = val * val;
  #pragma unroll
  for (int m = 1; m < 64; m <<= 1) ss += __shfl_xor(ss, m, 64);
  const float nv = val * (8.0f / fmaxf(sqrtf(ss), 1e-12f)) * g[h * DH + lane];
  const float pr = __shfl_xor(nv, 32, 64);         // partner element (d <-> d+32)
  const int fd = lane & 31;
  const float2 cs = ((const float2*)tab)[n * 32 + fd];   // (cos, sin)
  const float o = (lane < 32) ? (nv * cs.x - pr * cs.y) : (nv * cs.x + pr * cs.y);
  base[lane] = o;
}

// ---------------- K3: per-segment G_s = sk^T v (64x64), zc_s = sum sk ----------------
__global__ __launch_bounds__(256,1) void segG_kernel(const float* __restrict__ kw,
                                                     const float* __restrict__ vw,
                                                     float* __restrict__ G, float* __restrict__ zc){
  __shared__ float sk[SEG][DH];
  __shared__ float sv[SEG][DH];
  const int blk = blockIdx.x;           // bh*16 + s
  const int tid = threadIdx.x;
  const size_t segoff = ((size_t)(blk >> 4) * NTOT + (size_t)(blk & 15) * SEG) * DH;
  for (int i = tid; i < SEG*DH/4; i += 256){
    float4 kk = ((const float4*)(kw + segoff))[i];
    float4 s4;
    s4.x = kk.x > 0.f ? kk.x + 1.f : __expf(kk.x);
    s4.y = kk.y > 0.f ? kk.y + 1.f : __expf(kk.y);
    s4.z = kk.z > 0.f ? kk.z + 1.f : __expf(kk.z);
    s4.w = kk.w > 0.f ? kk.w + 1.f : __expf(kk.w);
    ((float4*)sk)[i] = s4;
    ((float4*)sv)[i] = ((const float4*)(vw + segoff))[i];
  }
  __syncthreads();
  const int d = tid >> 2, e0 = (tid & 3) * 16;
  float acc[16];
  #pragma unroll
  for (int e = 0; e < 16; e++) acc[e] = 0.f;
  float z = 0.f;
  for (int l = 0; l < SEG; l++){
    const float skd = sk[l][d];
    z += skd;
    #pragma unroll
    for (int e = 0; e < 16; e++) acc[e] += skd * sv[l][e0 + e];
  }
  float* Gout = G + (size_t)blk * DH * DH;
  #pragma unroll
  for (int e = 0; e < 16; e++) Gout[d*DH + e0 + e] = acc[e];
  if ((tid & 3) == 0) zc[(size_t)blk * DH + d] = z;
}

// ---------------- K4: exclusive prefix over segments -> Mp, zp ----------------
__global__ __launch_bounds__(256) void prefix_kernel(const float* __restrict__ G,
                                                     const float* __restrict__ zc,
                                                     float* __restrict__ Mp, float* __restrict__ zp){
  const int bh = blockIdx.x, tid = threadIdx.x;
  float run[16];
  #pragma unroll
  for (int k = 0; k < 16; k++) run[k] = 0.f;
  for (int s = 0; s < NSEG; s++){
    const size_t base = ((size_t)bh * NSEG + s) * DH * DH;
    #pragma unroll
    for (int k = 0; k < 16; k++){
      Mp[base + tid + 256*k] = run[k];
      run[k] += G[base + tid + 256*k];
    }
  }
  if (tid < DH){
    float rz = 0.f;
    for (int s = 0; s < NSEG; s++){
      zp[((size_t)bh*NSEG + s)*DH + tid] = rz;
      rz += zc[((size_t)bh*NSEG + s)*DH + tid];
    }
  }
}

// ---------------- K5: MFMA flash-attention per segment + gated memory readout ----------------
__global__ __launch_bounds__(256,1) void attn_mfma_kernel(
    const float* __restrict__ qw, const float* __restrict__ kw,
    const unsigned short* __restrict__ vt, const float* __restrict__ Mp,
    const float* __restrict__ zp, const float* __restrict__ beta,
    float* __restrict__ out)
{
  __shared__ unsigned short Qs[256*72];    // [row][d], stride 72 bf16
  __shared__ unsigned short KSs[256*72];   // K, later SQ*g/denm
  __shared__ unsigned short Vts[64*264];   // [e][j], stride 264
  __shared__ unsigned short Ps[4*64*72];   // per-wave P [i][j]
  __shared__ unsigned short Mts[64*72];    // M^T [e][d]
  __shared__ float den_s[256];
  __shared__ float zsh[64];

  const int blk = blockIdx.x;
  const int s = blk & 15, bh = blk >> 4;
  const int h = bh & 15, b = bh >> 4;
  const int tid = threadIdx.x;
  const int w = tid >> 6, lane = tid & 63;
  const int li = lane & 15, lg = lane >> 4;
  const size_t segoff = ((size_t)bh * NTOT + (size_t)s * SEG) * DH;

  #pragma unroll
  for (int it = 0; it < 16; it++){
    const int idx = tid + it*256;            // 4096 chunks of 4 f32
    const int row = idx >> 4, dc = idx & 15;
    float4 fq = *(const float4*)(qw + segoff + (size_t)row*64 + dc*4);
    float4 fk = *(const float4*)(kw + segoff + (size_t)row*64 + dc*4);
    uint2 pq, pk;
    pq.x = f2bf(fq.x) | ((unsigned)f2bf(fq.y) << 16);
    pq.y = f2bf(fq.z) | ((unsigned)f2bf(fq.w) << 16);
    pk.x = f2bf(fk.x) | ((unsigned)f2bf(fk.y) << 16);
    pk.y = f2bf(fk.z) | ((unsigned)f2bf(fk.w) << 16);
    *(uint2*)(Qs  + row*72 + dc*4) = pq;
    *(uint2*)(KSs + row*72 + dc*4) = pk;
  }
  #pragma unroll
  for (int it = 0; it < 8; it++){
    const int idx = tid + it*256;            // 2048 b128 chunks
    const int e = idx >> 5, jc = idx & 31;
    *(u32x4*)(Vts + e*264 + jc*8) =
      *(const u32x4*)(vt + (size_t)bh*DH*NTOT + (size_t)e*NTOT + s*SEG + jc*8);
  }
  #pragma unroll
  for (int it = 0; it < 16; it++){
    const int idx = tid + it*256;            // 4096 elems of Mp [d][e]
    const int d = idx >> 6, e = idx & 63;
    Mts[e*72 + d] = f2bf(Mp[(size_t)blk*4096 + d*64 + e]);
  }
  if (tid < 64) zsh[tid] = zp[(size_t)blk*64 + tid];
  __syncthreads();

  f32x4 o_acc[4][4] = {};
  float denr[4] = {0.f, 0.f, 0.f, 0.f};
  const int qrow0 = w*64;
  bf16x8 qf[4][2];
  #pragma unroll
  for (int it = 0; it < 4; it++)
    #pragma unroll
    for (int kb = 0; kb < 2; kb++)
      qf[it][kb] = *(const bf16x8*)(Qs + (qrow0 + it*16 + li)*72 + kb*32 + lg*8);

  for (int c = 0; c <= w; c++){
    f32x4 st[4][4] = {};
    #pragma unroll
    for (int jt = 0; jt < 4; jt++){
      bf16x8 kf0 = *(const bf16x8*)(KSs + (c*64 + jt*16 + li)*72 + 0  + lg*8);
      bf16x8 kf1 = *(const bf16x8*)(KSs + (c*64 + jt*16 + li)*72 + 32 + lg*8);
      #pragma unroll
      for (int it = 0; it < 4; it++){
        st[jt][it] = __builtin_amdgcn_mfma_f32_16x16x32_bf16(kf0, qf[it][0], st[jt][it], 0, 0, 0);
        st[jt][it] = __builtin_amdgcn_mfma_f32_16x16x32_bf16(kf1, qf[it][1], st[jt][it], 0, 0, 0);
      }
    }
    const bool diag = (c == w);
    #pragma unroll
    for (int jt = 0; jt < 4; jt++){
      #pragma unroll
      for (int it = 0; it < 4; it++){
        f32x4 p = st[jt][it];
        unsigned pb[4];
        #pragma unroll
        for (int r = 0; r < 4; r++){
          float pe = __expf(p[r] * 0.125f);
          if (diag && (jt*16 + lg*4 + r > it*16 + li)) pe = 0.f;
          pb[r] = __builtin_bit_cast(unsigned, pe) & 0xFFFF0000u;   // bf16 truncation
          p[r] = __builtin_bit_cast(float, pb[r]);                  // value actually used in PV
        }
        denr[it] += (p[0] + p[1]) + (p[2] + p[3]);
        uint2 pkk;
        pkk.x = (pb[0] >> 16) | pb[1];
        pkk.y = (pb[2] >> 16) | pb[3];
        *(uint2*)(Ps + w*4608 + (it*16 + li)*72 + jt*16 + lg*4) = pkk;
      }
    }
    bf16x8 pf[4][2];
    #pragma unroll
    for (int it = 0; it < 4; it++)
      #pragma unroll
      for (int kb = 0; kb < 2; kb++)
        pf[it][kb] = *(const bf16x8*)(Ps + w*4608 + (it*16 + li)*72 + kb*32 + lg*8);
    #pragma unroll
    for (int et = 0; et < 4; et++){
      bf16x8 vf0 = *(const bf16x8*)(Vts + (et*16 + li)*264 + c*64 + 0  + lg*8);
      bf16x8 vf1 = *(const bf16x8*)(Vts + (et*16 + li)*264 + c*64 + 32 + lg*8);
      #pragma unroll
      for (int it = 0; it < 4; it++){
        o_acc[it][et] = __builtin_amdgcn_mfma_f32_16x16x32_bf16(pf[it][0], vf0, o_acc[it][et], 0, 0, 0);
        o_acc[it][et] = __builtin_amdgcn_mfma_f32_16x16x32_bf16(pf[it][1], vf1, o_acc[it][et], 0, 0, 0);
      }
    }
  }

  #pragma unroll
  for (int it = 0; it < 4; it++){
    denr[it] += __shfl_xor(denr[it], 16, 64);
    denr[it] += __shfl_xor(denr[it], 32, 64);
  }
  if (lane < 16){
    #pragma unroll
    for (int it = 0; it < 4; it++) den_s[qrow0 + it*16 + lane] = denr[it];
  }
  const float gate = 1.f / (1.f + __expf(-beta[h]));
  __syncthreads();

  {
    const int i = tid;
    float sqv[64];
    float denm = 0.f;
    #pragma unroll
    for (int u = 0; u < 8; u++){
      bf16x8 qv = *(const bf16x8*)(Qs + i*72 + u*8);
      #pragma unroll
      for (int t2 = 0; t2 < 8; t2++){
        float x = __builtin_bit_cast(float, ((unsigned)(unsigned short)qv[t2]) << 16);
        float sq = x > 0.f ? x + 1.f : __expf(x);
        sqv[u*8 + t2] = sq;
        denm += sq * zsh[u*8 + t2];
      }
    }
    const float c2 = gate / (denm + 1e-6f);
    #pragma unroll
    for (int u = 0; u < 16; u++){
      uint2 pw;
      pw.x = f2bf(sqv[u*4]*c2)   | ((unsigned)f2bf(sqv[u*4+1]*c2) << 16);
      pw.y = f2bf(sqv[u*4+2]*c2) | ((unsigned)f2bf(sqv[u*4+3]*c2) << 16);
      *(uint2*)(KSs + i*72 + u*4) = pw;
    }
  }
  __syncthreads();

  #pragma unroll
  for (int it = 0; it < 4; it++){
    #pragma unroll
    for (int r = 0; r < 4; r++){
      const float c1 = (1.f - gate) / den_s[qrow0 + it*16 + lg*4 + r];
      #pragma unroll
      for (int et = 0; et < 4; et++) o_acc[it][et][r] *= c1;
    }
  }
  #pragma unroll
  for (int kb = 0; kb < 2; kb++){
    bf16x8 mf[4];
    #pragma unroll
    for (int et = 0; et < 4; et++)
      mf[et] = *(const bf16x8*)(Mts + (et*16 + li)*72 + kb*32 + lg*8);
    #pragma unroll
    for (int it = 0; it < 4; it++){
      bf16x8 sf = *(const bf16x8*)(KSs + (qrow0 + it*16 + li)*72 + kb*32 + lg*8);
      #pragma unroll
      for (int et = 0; et < 4; et++)
        o_acc[it][et] = __builtin_amdgcn_mfma_f32_16x16x32_bf16(sf, mf[et], o_acc[it][et], 0, 0, 0);
    }
  }

  #pragma unroll
  for (int it = 0; it < 4; it++){
    #pragma unroll
    for (int r = 0; r < 4; r++){
      const int n_g = s*SEG + qrow0 + it*16 + lg*4 + r;
      size_t o;
      if (n_g >= NA) o = ((size_t)b * NX + (size_t)(n_g - NA)) * 1024 + h * 64;
      else           o = 4194304u + ((size_t)b * NA + (size_t)n_g) * 1024 + h * 64;
      #pragma unroll
      for (int et = 0; et < 4; et++)
        out[o + et*16 + li] = o_acc[it][et][r];
    }
  }
}

extern "C" void kernel_launch(void* const* d_in, const int* in_sizes, int n_in,
                              void* d_out, int out_size, void* d_ws, size_t ws_size,
                              hipStream_t stream)
{
  (void)ws_size;
  const int expect[9] = {4194304, 4194304, 3145728, 3145728, 1024, 1024, 1024, 1024, 16};
  bool ok = (n_in == 9);
  if (ok) for (int i = 0; i < 9; i++) if (in_sizes[i] != expect[i]) { ok = false; break; }
  float* out = (float*)d_out;
  if (!ok){
    zero_kernel<<<dim3((out_size + 255)/256), dim3(256), 0, stream>>>(out, out_size);
    return;
  }

  const float* x    = (const float*)d_in[0];
  const float* a    = (const float*)d_in[1];
  const float* wx   = (const float*)d_in[2];
  const float* wa   = (const float*)d_in[3];
  const float* gqx  = (const float*)d_in[4];
  const float* gkx  = (const float*)d_in[5];
  const float* gqa  = (const float*)d_in[6];
  const float* gka  = (const float*)d_in[7];
  const float* beta = (const float*)d_in[8];

  char* wsb = (char*)d_ws;
  float* qw = (float*)wsb;                                   // 33,554,432 B
  float* kw = qw + 8388608;                                  // 33,554,432 B
  float* vw = kw + 8388608;                                  // 33,554,432 B
  unsigned short* Xb  = (unsigned short*)(wsb + 100663296);  //  8,388,608 B
  unsigned short* Ab  = Xb + 4194304;                        //  8,388,608 B
  unsigned short* WTx = Ab + 4194304;                        //  6,291,456 B
  unsigned short* WTa = WTx + 3145728;                       //  6,291,456 B
  unsigned short* vtb = Xb;                                  // 16,777,216 B (reuses Xb+Ab after GEMMs)
  float* ropetab = (float*)WTx;                              //  1,048,576 B (reuses WTx after GEMMs)
  float* G   = (float*)(wsb + 130023424);                    //  8,388,608 B
  float* Mp  = G + 2097152;                                  //  8,388,608 B
  float* zc  = Mp + 2097152;                                 //    131,072 B
  float* zpb = zc + 32768;                                   //    131,072 B  (total ~147 MB)

  cvt_kernel<<<dim3(4096), dim3(256), 0, stream>>>(x, Xb, 1048576);
  cvt_kernel<<<dim3(4096), dim3(256), 0, stream>>>(a, Ab, 1048576);
  wtr_kernel<<<dim3(96,32), dim3(32,8), 0, stream>>>(wx, WTx);
  wtr_kernel<<<dim3(96,32), dim3(32,8), 0, stream>>>(wa, WTa);
  // a tokens occupy concatenated positions [0,2048); x tokens [2048,4096)
  gemm_qkv_kernel<<<dim3(24,32), dim3(256), 0, stream>>>(Xb, WTx, qw, kw, vw, 2048);
  gemm_qkv_kernel<<<dim3(24,32), dim3(256), 0, stream>>>(Ab, WTa, qw, kw, vw, 0);
  vtr_kernel<<<dim3(128, 2, 32), dim3(32,8), 0, stream>>>(vw, vtb);        // after GEMMs (reuses Xb/Ab)
  rope_tab_kernel<<<dim3(512), dim3(256), 0, stream>>>(ropetab);           // after GEMMs (reuses WTx)
  normrope_kernel<<<dim3(65536), dim3(256), 0, stream>>>(qw, kw, gqx, gkx, gqa, gka, ropetab);
  segG_kernel<<<dim3(512), dim3(256), 0, stream>>>(kw, vw, G, zc);
  prefix_kernel<<<dim3(32), dim3(256), 0, stream>>>(G, zc, Mp, zpb);
  attn_mfma_kernel<<<dim3(512), dim3(256), 0, stream>>>(qw, kw, vtb, Mp, zpb, beta, out);
}

// Round 16
// 212.587 us; speedup vs baseline: 2.1864x; 1.1353x over previous
//
#include <hip/hip_runtime.h>

#define HEADS 16
#define DH    64
#define NA    2048
#define NX    2048
#define NTOT  4096
#define DIMK  1024
#define NQKV  3072
#define SEG   256
#define NSEG  16

typedef float          f32x4  __attribute__((ext_vector_type(4)));
typedef short          bf16x8 __attribute__((ext_vector_type(8)));
typedef unsigned int   u32x4  __attribute__((ext_vector_type(4)));

// f32 -> bf16 bits, round-to-nearest-even (finite inputs)
__device__ __forceinline__ unsigned short f2bf(float f){
  unsigned int u = __builtin_bit_cast(unsigned int, f);
  unsigned int r = 0x7fffu + ((u >> 16) & 1u);
  return (unsigned short)((u + r) >> 16);
}

__global__ __launch_bounds__(256) void zero_kernel(float* __restrict__ out, int n){
  int i = blockIdx.x * 256 + threadIdx.x;
  if (i < n) out[i] = 0.f;
}

// ---------------- K0a: f32 -> bf16 elementwise ----------------
__global__ __launch_bounds__(256) void cvt_kernel(const float* __restrict__ src,
                                                  unsigned short* __restrict__ dst, int n4){
  int i = blockIdx.x * 256 + threadIdx.x;
  if (i >= n4) return;
  float4 v = ((const float4*)src)[i];
  ushort4 o;
  o.x = f2bf(v.x); o.y = f2bf(v.y); o.z = f2bf(v.z); o.w = f2bf(v.w);
  ((ushort4*)dst)[i] = o;
}

// ---------------- K0b: W [DIMK][NQKV] f32 -> WT [NQKV][DIMK] bf16 ----------------
__global__ __launch_bounds__(256) void wtr_kernel(const float* __restrict__ W,
                                                  unsigned short* __restrict__ WT){
  __shared__ float tile[32][33];
  int c0 = blockIdx.x * 32, k0 = blockIdx.y * 32;
  int tx = threadIdx.x, ty = threadIdx.y;
  #pragma unroll
  for (int i = 0; i < 32; i += 8) tile[ty+i][tx] = W[(size_t)(k0+ty+i)*NQKV + c0 + tx];
  __syncthreads();
  #pragma unroll
  for (int i = 0; i < 32; i += 8) WT[(size_t)(c0+ty+i)*DIMK + k0 + tx] = f2bf(tile[tx][ty+i]);
}

// ---------------- K0c: vw (b,h,n,d) f32 -> vt (b,h,d,n) bf16 ----------------
__global__ __launch_bounds__(256) void vtr_kernel(const float* __restrict__ vw,
                                                  unsigned short* __restrict__ vt){
  __shared__ float tile[32][33];
  const int nt = blockIdx.x, dt = blockIdx.y, bh = blockIdx.z;
  const int tx = threadIdx.x, ty = threadIdx.y;
  const size_t base = (size_t)bh * NTOT * DH;
  #pragma unroll
  for (int i = 0; i < 32; i += 8)
    tile[ty+i][tx] = vw[base + (size_t)(nt*32 + ty+i)*DH + dt*32 + tx];
  __syncthreads();
  #pragma unroll
  for (int i = 0; i < 32; i += 8)
    vt[(size_t)bh*DH*NTOT + (size_t)(dt*32 + ty+i)*NTOT + nt*32 + tx] = f2bf(tile[tx][ty+i]);
}

// ---------------- K0d: exact RoPE cos/sin table [n][d][2], 131072 entries ----------------
__global__ __launch_bounds__(256) void rope_tab_kernel(float* __restrict__ tab){
  const int idx = blockIdx.x * 256 + threadIdx.x;   // < 131072
  const int n = idx >> 5, d = idx & 31;
  const float ang = (float)n * expf(-(float)d * 0.28782313662425572f);  // n * 10000^(-d/32)
  float sn, cs;
  sincosf(ang, &sn, &cs);
  float2 p; p.x = cs; p.y = sn;
  ((float2*)tab)[idx] = p;
}

// ---------------- K1: bf16 MFMA GEMM, scatter into q/k/v (b,h,n,d) f32 ----------------
__global__ __launch_bounds__(256,2) void gemm_qkv_kernel(
    const unsigned short* __restrict__ Xb, const unsigned short* __restrict__ WT,
    float* __restrict__ qw, float* __restrict__ kw, float* __restrict__ vw, const int n_off)
{
  __shared__ __align__(16) unsigned short As[128*32];
  __shared__ __align__(16) unsigned short Bs[128*32];
  const int tid  = threadIdx.x;
  const int lane = tid & 63, w = tid >> 6;
  const int wr = w >> 1, wc = w & 1;
  const int m0 = blockIdx.y * 128, c0 = blockIdx.x * 128;

  f32x4 acc[4][4] = {};

  for (int k0 = 0; k0 < DIMK; k0 += 32){
    __syncthreads();
    #pragma unroll
    for (int cc = 0; cc < 2; cc++){
      const int c = tid*2 + cc;
      const int row = c >> 2, slot = c & 3;
      const int gs = slot ^ (row & 3);
      *(u32x4*)(&As[row*32 + slot*8]) = *(const u32x4*)(Xb + (size_t)(m0+row)*DIMK + k0 + gs*8);
      *(u32x4*)(&Bs[row*32 + slot*8]) = *(const u32x4*)(WT + (size_t)(c0+row)*DIMK + k0 + gs*8);
    }
    __syncthreads();
    bf16x8 af[4], bf[4];
    const int kc = lane >> 4;
    #pragma unroll
    for (int m = 0; m < 4; m++){
      const int r = wr*64 + m*16 + (lane & 15);
      af[m] = *(const bf16x8*)(&As[r*32 + ((kc ^ (r & 3)) * 8)]);
    }
    #pragma unroll
    for (int n = 0; n < 4; n++){
      const int r = wc*64 + n*16 + (lane & 15);
      bf[n] = *(const bf16x8*)(&Bs[r*32 + ((kc ^ (r & 3)) * 8)]);
    }
    #pragma unroll
    for (int m = 0; m < 4; m++)
      #pragma unroll
      for (int n = 0; n < 4; n++)
        acc[m][n] = __builtin_amdgcn_mfma_f32_16x16x32_bf16(af[m], bf[n], acc[m][n], 0, 0, 0);
  }

  #pragma unroll
  for (int m = 0; m < 4; m++){
    #pragma unroll
    for (int r4 = 0; r4 < 4; r4++){
      const int row = m0 + wr*64 + m*16 + ((lane >> 4) * 4) + r4;
      const int bb = row >> 11, nn = row & 2047;
      #pragma unroll
      for (int n = 0; n < 4; n++){
        const int col = c0 + wc*64 + n*16 + (lane & 15);
        const int which = col >> 10;
        const int h = (col >> 6) & 15, d = col & 63;
        float* dst = (which == 0) ? qw : ((which == 1) ? kw : vw);
        dst[(((size_t)(bb*HEADS + h))*NTOT + (size_t)(nn + n_off))*DH + d] = acc[m][n][r4];
      }
    }
  }
}

// ---------------- K2: wave-per-row mh_rmsnorm + RoPE (coalesced, no arrays) ----------------
__global__ __launch_bounds__(256) void normrope_kernel(
    float* __restrict__ qw, float* __restrict__ kw,
    const float* __restrict__ gqx, const float* __restrict__ gkx,
    const float* __restrict__ gqa, const float* __restrict__ gka,
    const float* __restrict__ tab)
{
  const int gtid = blockIdx.x * 256 + threadIdx.x;
  const int R    = gtid >> 6;          // row 0..262143
  const int lane = gtid & 63;          // dim
  const int t    = R >> 17;            // 0=q, 1=k
  const int r    = R & 131071;         // (b*16+h)*4096 + n
  const int n    = r & 4095;
  const int h    = (r >> 12) & 15;
  float* base = (t == 0 ? qw : kw) + (size_t)r * DH;
  const float* g = (t == 0) ? (n < NA ? gqa : gqx) : (n < NA ? gka : gkx);

  const float val = base[lane];
  float ss = val * val;
  #pragma unroll
  for (int m = 1; m < 64; m <<= 1) ss += __shfl_xor(ss, m, 64);
  const float nv = val * (8.0f / fmaxf(sqrtf(ss), 1e-12f)) * g[h * DH + lane];
  const float pr = __shfl_xor(nv, 32, 64);         // partner element (d <-> d+32)
  const int fd = lane & 31;
  const float2 cs = ((const float2*)tab)[n * 32 + fd];   // (cos, sin)
  const float o = (lane < 32) ? (nv * cs.x - pr * cs.y) : (nv * cs.x + pr * cs.y);
  base[lane] = o;
}

// ---------------- K3: MFMA segG: G = skT (64x256) x v (256x64), zc = row-sum(skT) ----------------
// Reuses the session-verified frag conventions: both operands [dim][k], D row=lg*4+r, col=li.
__global__ __launch_bounds__(256,2) void segG_kernel(const float* __restrict__ kw,
                                                     const unsigned short* __restrict__ vt,
                                                     float* __restrict__ G, float* __restrict__ zc){
  __shared__ unsigned short skT[64*264];   // [d][l], stride 264
  __shared__ unsigned short Vts[64*264];   // [e][l], stride 264
  const int blk = blockIdx.x;              // bh*16 + s
  const int bh = blk >> 4, s = blk & 15;
  const int tid = threadIdx.x;
  const int w = tid >> 6, lane = tid & 63;
  const int li = lane & 15, lg = lane >> 4;
  const size_t segoff = ((size_t)bh * NTOT + (size_t)s * SEG) * DH;

  // stage Vt tile (bf16, coalesced b128 from pre-transposed global)
  #pragma unroll
  for (int it = 0; it < 8; it++){
    const int idx = tid + it*256;          // 2048 b128 chunks
    const int e = idx >> 5, jc = idx & 31;
    *(u32x4*)(Vts + e*264 + jc*8) =
      *(const u32x4*)(vt + (size_t)bh*DH*NTOT + (size_t)e*NTOT + s*SEG + jc*8);
  }
  // stage skT = elu(k)+1, transposed in-LDS (f32 math, RTNE->bf16)
  #pragma unroll
  for (int it = 0; it < 16; it++){
    const int idx = tid + it*256;          // 4096 float4 chunks
    const int l = idx >> 4, dc = idx & 15;
    float4 f = *(const float4*)(kw + segoff + (size_t)l*64 + dc*4);
    skT[(dc*4+0)*264 + l] = f2bf(f.x > 0.f ? f.x + 1.f : __expf(f.x));
    skT[(dc*4+1)*264 + l] = f2bf(f.y > 0.f ? f.y + 1.f : __expf(f.y));
    skT[(dc*4+2)*264 + l] = f2bf(f.z > 0.f ? f.z + 1.f : __expf(f.z));
    skT[(dc*4+3)*264 + l] = f2bf(f.w > 0.f ? f.w + 1.f : __expf(f.w));
  }
  __syncthreads();

  // zc: 4 threads per d-row, each sums 64 of 256, combine via shfl quartet
  {
    const int d = tid >> 2, q = tid & 3;
    float zz = 0.f;
    #pragma unroll
    for (int u = 0; u < 8; u++){
      bf16x8 vv = *(const bf16x8*)(skT + d*264 + q*64 + u*8);
      #pragma unroll
      for (int t2 = 0; t2 < 8; t2++)
        zz += __builtin_bit_cast(float, ((unsigned)(unsigned short)vv[t2]) << 16);
    }
    zz += __shfl_xor(zz, 1, 64);
    zz += __shfl_xor(zz, 2, 64);
    if (q == 0) zc[(size_t)blk*64 + d] = zz;
  }

  // MFMA: wave w owns G rows [w*16, w*16+16)
  f32x4 acc[4] = {};
  #pragma unroll
  for (int k0 = 0; k0 < 256; k0 += 32){
    bf16x8 af = *(const bf16x8*)(skT + (w*16 + li)*264 + k0 + lg*8);
    #pragma unroll
    for (int n = 0; n < 4; n++){
      bf16x8 bf = *(const bf16x8*)(Vts + (n*16 + li)*264 + k0 + lg*8);
      acc[n] = __builtin_amdgcn_mfma_f32_16x16x32_bf16(af, bf, acc[n], 0, 0, 0);
    }
  }
  float* Gout = G + (size_t)blk * DH * DH;
  #pragma unroll
  for (int n = 0; n < 4; n++)
    #pragma unroll
    for (int r = 0; r < 4; r++)
      Gout[(w*16 + lg*4 + r)*64 + n*16 + li] = acc[n][r];
}

// ---------------- K4: exclusive prefix over segments -> Mp, zp ----------------
__global__ __launch_bounds__(256) void prefix_kernel(const float* __restrict__ G,
                                                     const float* __restrict__ zc,
                                                     float* __restrict__ Mp, float* __restrict__ zp){
  const int bh = blockIdx.x, tid = threadIdx.x;
  float run[16];
  #pragma unroll
  for (int k = 0; k < 16; k++) run[k] = 0.f;
  for (int s = 0; s < NSEG; s++){
    const size_t base = ((size_t)bh * NSEG + s) * DH * DH;
    #pragma unroll
    for (int k = 0; k < 16; k++){
      Mp[base + tid + 256*k] = run[k];
      run[k] += G[base + tid + 256*k];
    }
  }
  if (tid < DH){
    float rz = 0.f;
    for (int s = 0; s < NSEG; s++){
      zp[((size_t)bh*NSEG + s)*DH + tid] = rz;
      rz += zc[((size_t)bh*NSEG + s)*DH + tid];
    }
  }
}

// ---------------- K5: MFMA flash-attention per segment + gated memory readout ----------------
__global__ __launch_bounds__(256,1) void attn_mfma_kernel(
    const float* __restrict__ qw, const float* __restrict__ kw,
    const unsigned short* __restrict__ vt, const float* __restrict__ Mp,
    const float* __restrict__ zp, const float* __restrict__ beta,
    float* __restrict__ out)
{
  __shared__ unsigned short Qs[256*72];    // [row][d], stride 72 bf16
  __shared__ unsigned short KSs[256*72];   // K, later SQ*g/denm
  __shared__ unsigned short Vts[64*264];   // [e][j], stride 264
  __shared__ unsigned short Ps[4*64*72];   // per-wave P [i][j]
  __shared__ unsigned short Mts[64*72];    // M^T [e][d]
  __shared__ float den_s[256];
  __shared__ float zsh[64];

  const int blk = blockIdx.x;
  const int s = blk & 15, bh = blk >> 4;
  const int h = bh & 15, b = bh >> 4;
  const int tid = threadIdx.x;
  const int w = tid >> 6, lane = tid & 63;
  const int li = lane & 15, lg = lane >> 4;
  const size_t segoff = ((size_t)bh * NTOT + (size_t)s * SEG) * DH;

  #pragma unroll
  for (int it = 0; it < 16; it++){
    const int idx = tid + it*256;            // 4096 chunks of 4 f32
    const int row = idx >> 4, dc = idx & 15;
    float4 fq = *(const float4*)(qw + segoff + (size_t)row*64 + dc*4);
    float4 fk = *(const float4*)(kw + segoff + (size_t)row*64 + dc*4);
    uint2 pq, pk;
    pq.x = f2bf(fq.x) | ((unsigned)f2bf(fq.y) << 16);
    pq.y = f2bf(fq.z) | ((unsigned)f2bf(fq.w) << 16);
    pk.x = f2bf(fk.x) | ((unsigned)f2bf(fk.y) << 16);
    pk.y = f2bf(fk.z) | ((unsigned)f2bf(fk.w) << 16);
    *(uint2*)(Qs  + row*72 + dc*4) = pq;
    *(uint2*)(KSs + row*72 + dc*4) = pk;
  }
  #pragma unroll
  for (int it = 0; it < 8; it++){
    const int idx = tid + it*256;            // 2048 b128 chunks
    const int e = idx >> 5, jc = idx & 31;
    *(u32x4*)(Vts + e*264 + jc*8) =
      *(const u32x4*)(vt + (size_t)bh*DH*NTOT + (size_t)e*NTOT + s*SEG + jc*8);
  }
  #pragma unroll
  for (int it = 0; it < 16; it++){
    const int idx = tid + it*256;            // 4096 elems of Mp [d][e]
    const int d = idx >> 6, e = idx & 63;
    Mts[e*72 + d] = f2bf(Mp[(size_t)blk*4096 + d*64 + e]);
  }
  if (tid < 64) zsh[tid] = zp[(size_t)blk*64 + tid];
  __syncthreads();

  f32x4 o_acc[4][4] = {};
  float denr[4] = {0.f, 0.f, 0.f, 0.f};
  const int qrow0 = w*64;
  bf16x8 qf[4][2];
  #pragma unroll
  for (int it = 0; it < 4; it++)
    #pragma unroll
    for (int kb = 0; kb < 2; kb++)
      qf[it][kb] = *(const bf16x8*)(Qs + (qrow0 + it*16 + li)*72 + kb*32 + lg*8);

  for (int c = 0; c <= w; c++){
    f32x4 st[4][4] = {};
    #pragma unroll
    for (int jt = 0; jt < 4; jt++){
      bf16x8 kf0 = *(const bf16x8*)(KSs + (c*64 + jt*16 + li)*72 + 0  + lg*8);
      bf16x8 kf1 = *(const bf16x8*)(KSs + (c*64 + jt*16 + li)*72 + 32 + lg*8);
      #pragma unroll
      for (int it = 0; it < 4; it++){
        st[jt][it] = __builtin_amdgcn_mfma_f32_16x16x32_bf16(kf0, qf[it][0], st[jt][it], 0, 0, 0);
        st[jt][it] = __builtin_amdgcn_mfma_f32_16x16x32_bf16(kf1, qf[it][1], st[jt][it], 0, 0, 0);
      }
    }
    const bool diag = (c == w);
    #pragma unroll
    for (int jt = 0; jt < 4; jt++){
      #pragma unroll
      for (int it = 0; it < 4; it++){
        f32x4 p = st[jt][it];
        unsigned pb[4];
        #pragma unroll
        for (int r = 0; r < 4; r++){
          float pe = __expf(p[r] * 0.125f);
          if (diag && (jt*16 + lg*4 + r > it*16 + li)) pe = 0.f;
          pb[r] = __builtin_bit_cast(unsigned, pe) & 0xFFFF0000u;   // bf16 truncation
          p[r] = __builtin_bit_cast(float, pb[r]);                  // value actually used in PV
        }
        denr[it] += (p[0] + p[1]) + (p[2] + p[3]);
        uint2 pkk;
        pkk.x = (pb[0] >> 16) | pb[1];
        pkk.y = (pb[2] >> 16) | pb[3];
        *(uint2*)(Ps + w*4608 + (it*16 + li)*72 + jt*16 + lg*4) = pkk;
      }
    }
    bf16x8 pf[4][2];
    #pragma unroll
    for (int it = 0; it < 4; it++)
      #pragma unroll
      for (int kb = 0; kb < 2; kb++)
        pf[it][kb] = *(const bf16x8*)(Ps + w*4608 + (it*16 + li)*72 + kb*32 + lg*8);
    #pragma unroll
    for (int et = 0; et < 4; et++){
      bf16x8 vf0 = *(const bf16x8*)(Vts + (et*16 + li)*264 + c*64 + 0  + lg*8);
      bf16x8 vf1 = *(const bf16x8*)(Vts + (et*16 + li)*264 + c*64 + 32 + lg*8);
      #pragma unroll
      for (int it = 0; it < 4; it++){
        o_acc[it][et] = __builtin_amdgcn_mfma_f32_16x16x32_bf16(pf[it][0], vf0, o_acc[it][et], 0, 0, 0);
        o_acc[it][et] = __builtin_amdgcn_mfma_f32_16x16x32_bf16(pf[it][1], vf1, o_acc[it][et], 0, 0, 0);
      }
    }
  }

  #pragma unroll
  for (int it = 0; it < 4; it++){
    denr[it] += __shfl_xor(denr[it], 16, 64);
    denr[it] += __shfl_xor(denr[it], 32, 64);
  }
  if (lane < 16){
    #pragma unroll
    for (int it = 0; it < 4; it++) den_s[qrow0 + it*16 + lane] = denr[it];
  }
  const float gate = 1.f / (1.f + __expf(-beta[h]));
  __syncthreads();

  {
    const int i = tid;
    float sqv[64];
    float denm = 0.f;
    #pragma unroll
    for (int u = 0; u < 8; u++){
      bf16x8 qv = *(const bf16x8*)(Qs + i*72 + u*8);
      #pragma unroll
      for (int t2 = 0; t2 < 8; t2++){
        float x = __builtin_bit_cast(float, ((unsigned)(unsigned short)qv[t2]) << 16);
        float sq = x > 0.f ? x + 1.f : __expf(x);
        sqv[u*8 + t2] = sq;
        denm += sq * zsh[u*8 + t2];
      }
    }
    const float c2 = gate / (denm + 1e-6f);
    #pragma unroll
    for (int u = 0; u < 16; u++){
      uint2 pw;
      pw.x = f2bf(sqv[u*4]*c2)   | ((unsigned)f2bf(sqv[u*4+1]*c2) << 16);
      pw.y = f2bf(sqv[u*4+2]*c2) | ((unsigned)f2bf(sqv[u*4+3]*c2) << 16);
      *(uint2*)(KSs + i*72 + u*4) = pw;
    }
  }
  __syncthreads();

  #pragma unroll
  for (int it = 0; it < 4; it++){
    #pragma unroll
    for (int r = 0; r < 4; r++){
      const float c1 = (1.f - gate) / den_s[qrow0 + it*16 + lg*4 + r];
      #pragma unroll
      for (int et = 0; et < 4; et++) o_acc[it][et][r] *= c1;
    }
  }
  #pragma unroll
  for (int kb = 0; kb < 2; kb++){
    bf16x8 mf[4];
    #pragma unroll
    for (int et = 0; et < 4; et++)
      mf[et] = *(const bf16x8*)(Mts + (et*16 + li)*72 + kb*32 + lg*8);
    #pragma unroll
    for (int it = 0; it < 4; it++){
      bf16x8 sf = *(const bf16x8*)(KSs + (qrow0 + it*16 + li)*72 + kb*32 + lg*8);
      #pragma unroll
      for (int et = 0; et < 4; et++)
        o_acc[it][et] = __builtin_amdgcn_mfma_f32_16x16x32_bf16(sf, mf[et], o_acc[it][et], 0, 0, 0);
    }
  }

  #pragma unroll
  for (int it = 0; it < 4; it++){
    #pragma unroll
    for (int r = 0; r < 4; r++){
      const int n_g = s*SEG + qrow0 + it*16 + lg*4 + r;
      size_t o;
      if (n_g >= NA) o = ((size_t)b * NX + (size_t)(n_g - NA)) * 1024 + h * 64;
      else           o = 4194304u + ((size_t)b * NA + (size_t)n_g) * 1024 + h * 64;
      #pragma unroll
      for (int et = 0; et < 4; et++)
        out[o + et*16 + li] = o_acc[it][et][r];
    }
  }
}

extern "C" void kernel_launch(void* const* d_in, const int* in_sizes, int n_in,
                              void* d_out, int out_size, void* d_ws, size_t ws_size,
                              hipStream_t stream)
{
  (void)ws_size;
  const int expect[9] = {4194304, 4194304, 3145728, 3145728, 1024, 1024, 1024, 1024, 16};
  bool ok = (n_in == 9);
  if (ok) for (int i = 0; i < 9; i++) if (in_sizes[i] != expect[i]) { ok = false; break; }
  float* out = (float*)d_out;
  if (!ok){
    zero_kernel<<<dim3((out_size + 255)/256), dim3(256), 0, stream>>>(out, out_size);
    return;
  }

  const float* x    = (const float*)d_in[0];
  const float* a    = (const float*)d_in[1];
  const float* wx   = (const float*)d_in[2];
  const float* wa   = (const float*)d_in[3];
  const float* gqx  = (const float*)d_in[4];
  const float* gkx  = (const float*)d_in[5];
  const float* gqa  = (const float*)d_in[6];
  const float* gka  = (const float*)d_in[7];
  const float* beta = (const float*)d_in[8];

  char* wsb = (char*)d_ws;
  float* qw = (float*)wsb;                                   // 33,554,432 B
  float* kw = qw + 8388608;                                  // 33,554,432 B
  float* vw = kw + 8388608;                                  // 33,554,432 B
  unsigned short* Xb  = (unsigned short*)(wsb + 100663296);  //  8,388,608 B
  unsigned short* Ab  = Xb + 4194304;                        //  8,388,608 B
  unsigned short* WTx = Ab + 4194304;                        //  6,291,456 B
  unsigned short* WTa = WTx + 3145728;                       //  6,291,456 B
  unsigned short* vtb = Xb;                                  // 16,777,216 B (reuses Xb+Ab after GEMMs)
  float* ropetab = (float*)WTx;                              //  1,048,576 B (reuses WTx after GEMMs)
  float* G   = (float*)(wsb + 130023424);                    //  8,388,608 B
  float* Mp  = G + 2097152;                                  //  8,388,608 B
  float* zc  = Mp + 2097152;                                 //    131,072 B
  float* zpb = zc + 32768;                                   //    131,072 B  (total ~147 MB)

  cvt_kernel<<<dim3(4096), dim3(256), 0, stream>>>(x, Xb, 1048576);
  cvt_kernel<<<dim3(4096), dim3(256), 0, stream>>>(a, Ab, 1048576);
  wtr_kernel<<<dim3(96,32), dim3(32,8), 0, stream>>>(wx, WTx);
  wtr_kernel<<<dim3(96,32), dim3(32,8), 0, stream>>>(wa, WTa);
  // a tokens occupy concatenated positions [0,2048); x tokens [2048,4096)
  gemm_qkv_kernel<<<dim3(24,32), dim3(256), 0, stream>>>(Xb, WTx, qw, kw, vw, 2048);
  gemm_qkv_kernel<<<dim3(24,32), dim3(256), 0, stream>>>(Ab, WTa, qw, kw, vw, 0);
  vtr_kernel<<<dim3(128, 2, 32), dim3(32,8), 0, stream>>>(vw, vtb);        // after GEMMs (reuses Xb/Ab)
  rope_tab_kernel<<<dim3(512), dim3(256), 0, stream>>>(ropetab);           // after GEMMs (reuses WTx)
  normrope_kernel<<<dim3(65536), dim3(256), 0, stream>>>(qw, kw, gqx, gkx, gqa, gka, ropetab);
  segG_kernel<<<dim3(512), dim3(256), 0, stream>>>(kw, vtb, G, zc);
  prefix_kernel<<<dim3(32), dim3(256), 0, stream>>>(G, zc, Mp, zpb);
  attn_mfma_kernel<<<dim3(512), dim3(256), 0, stream>>>(qw, kw, vtb, Mp, zpb, beta, out);
}

// Round 17
// 165.543 us; speedup vs baseline: 2.8077x; 1.2842x over previous
//
#include <hip/hip_runtime.h>

#define HEADS 16
#define DH    64
#define NA    2048
#define NX    2048
#define NTOT  4096
#define DIMK  1024
#define NQKV  3072
#define SEG   256
#define NSEG  16

typedef float          f32x4  __attribute__((ext_vector_type(4)));
typedef short          bf16x8 __attribute__((ext_vector_type(8)));
typedef unsigned int   u32x4  __attribute__((ext_vector_type(4)));

// f32 -> bf16 bits, round-to-nearest-even (finite inputs)
__device__ __forceinline__ unsigned short f2bf(float f){
  unsigned int u = __builtin_bit_cast(unsigned int, f);
  unsigned int r = 0x7fffu + ((u >> 16) & 1u);
  return (unsigned short)((u + r) >> 16);
}
__device__ __forceinline__ float bf2f(unsigned short u){
  return __builtin_bit_cast(float, ((unsigned int)u) << 16);
}

__global__ __launch_bounds__(256) void zero_kernel(float* __restrict__ out, int n){
  int i = blockIdx.x * 256 + threadIdx.x;
  if (i < n) out[i] = 0.f;
}

// ---------------- K0a: f32 -> bf16 elementwise ----------------
__global__ __launch_bounds__(256) void cvt_kernel(const float* __restrict__ src,
                                                  unsigned short* __restrict__ dst, int n4){
  int i = blockIdx.x * 256 + threadIdx.x;
  if (i >= n4) return;
  float4 v = ((const float4*)src)[i];
  ushort4 o;
  o.x = f2bf(v.x); o.y = f2bf(v.y); o.z = f2bf(v.z); o.w = f2bf(v.w);
  ((ushort4*)dst)[i] = o;
}

// ---------------- K0b: W [DIMK][NQKV] f32 -> WT [NQKV][DIMK] bf16 ----------------
__global__ __launch_bounds__(256) void wtr_kernel(const float* __restrict__ W,
                                                  unsigned short* __restrict__ WT){
  __shared__ float tile[32][33];
  int c0 = blockIdx.x * 32, k0 = blockIdx.y * 32;
  int tx = threadIdx.x, ty = threadIdx.y;
  #pragma unroll
  for (int i = 0; i < 32; i += 8) tile[ty+i][tx] = W[(size_t)(k0+ty+i)*NQKV + c0 + tx];
  __syncthreads();
  #pragma unroll
  for (int i = 0; i < 32; i += 8) WT[(size_t)(c0+ty+i)*DIMK + k0 + tx] = f2bf(tile[tx][ty+i]);
}

// ---------------- K0d: exact RoPE cos/sin table [n][fd][2], 131072 entries ----------------
__global__ __launch_bounds__(256) void rope_tab_kernel(float* __restrict__ tab){
  const int idx = blockIdx.x * 256 + threadIdx.x;   // < 131072
  const int n = idx >> 5, d = idx & 31;
  const float ang = (float)n * expf(-(float)d * 0.28782313662425572f);  // n * 10000^(-d/32)
  float sn, cs;
  sincosf(ang, &sn, &cs);
  float2 p; p.x = cs; p.y = sn;
  ((float2*)tab)[idx] = p;
}

// ---------------- K1: bf16 MFMA GEMM with FUSED rmsnorm+RoPE epilogue ----------------
// q/k waves: in-register per-head rmsnorm (shfl over li) + table RoPE -> bf16 [bh][n][d]
// v waves: transposed bf16 store -> vt [bh][d][n]
__global__ __launch_bounds__(256,2) void gemm_qkv_kernel(
    const unsigned short* __restrict__ Xb, const unsigned short* __restrict__ WT,
    unsigned short* __restrict__ qb, unsigned short* __restrict__ kb,
    unsigned short* __restrict__ vt, const int n_off,
    const float* __restrict__ gq, const float* __restrict__ gk,
    const float* __restrict__ tab)
{
  __shared__ __align__(16) unsigned short As[128*32];
  __shared__ __align__(16) unsigned short Bs[128*32];
  const int tid  = threadIdx.x;
  const int lane = tid & 63, w = tid >> 6;
  const int wr = w >> 1, wc = w & 1;
  const int li = lane & 15, lg = lane >> 4;
  const int m0 = blockIdx.y * 128, c0 = blockIdx.x * 128;

  f32x4 acc[4][4] = {};

  for (int k0 = 0; k0 < DIMK; k0 += 32){
    __syncthreads();
    #pragma unroll
    for (int cc = 0; cc < 2; cc++){
      const int c = tid*2 + cc;
      const int row = c >> 2, slot = c & 3;
      const int gs = slot ^ (row & 3);
      *(u32x4*)(&As[row*32 + slot*8]) = *(const u32x4*)(Xb + (size_t)(m0+row)*DIMK + k0 + gs*8);
      *(u32x4*)(&Bs[row*32 + slot*8]) = *(const u32x4*)(WT + (size_t)(c0+row)*DIMK + k0 + gs*8);
    }
    __syncthreads();
    bf16x8 af[4], bf[4];
    const int kc = lane >> 4;
    #pragma unroll
    for (int m = 0; m < 4; m++){
      const int r = wr*64 + m*16 + li;
      af[m] = *(const bf16x8*)(&As[r*32 + ((kc ^ (r & 3)) * 8)]);
    }
    #pragma unroll
    for (int n = 0; n < 4; n++){
      const int r = wc*64 + n*16 + li;
      bf[n] = *(const bf16x8*)(&Bs[r*32 + ((kc ^ (r & 3)) * 8)]);
    }
    #pragma unroll
    for (int m = 0; m < 4; m++)
      #pragma unroll
      for (int n = 0; n < 4; n++)
        acc[m][n] = __builtin_amdgcn_mfma_f32_16x16x32_bf16(af[m], bf[n], acc[m][n], 0, 0, 0);
  }

  const int colbase = c0 + wc*64;           // multiple of 64; one head per wave
  const int which = colbase >> 10;          // 0=q, 1=k, 2=v (wave-uniform)
  const int h = (colbase >> 6) & 15;

  if (which < 2){
    const float* gv = (which == 0) ? gq : gk;
    unsigned short* dstb = (which == 0) ? qb : kb;
    float gl[4];
    #pragma unroll
    for (int n = 0; n < 4; n++) gl[n] = gv[h*64 + n*16 + li];
    #pragma unroll
    for (int m = 0; m < 4; m++){
      #pragma unroll
      for (int r = 0; r < 4; r++){
        float ss = acc[m][0][r]*acc[m][0][r] + acc[m][1][r]*acc[m][1][r]
                 + acc[m][2][r]*acc[m][2][r] + acc[m][3][r]*acc[m][3][r];
        ss += __shfl_xor(ss, 1, 64);
        ss += __shfl_xor(ss, 2, 64);
        ss += __shfl_xor(ss, 4, 64);
        ss += __shfl_xor(ss, 8, 64);
        const float sc = 8.0f / fmaxf(sqrtf(ss), 1e-12f);
        float v0 = acc[m][0][r]*sc*gl[0], v1 = acc[m][1][r]*sc*gl[1];
        float v2 = acc[m][2][r]*sc*gl[2], v3 = acc[m][3][r]*sc*gl[3];
        const int row = m0 + wr*64 + m*16 + lg*4 + r;
        const int bb = row >> 11, nn = row & 2047;
        const int n_g = nn + n_off;
        const float2 cs0 = ((const float2*)tab)[n_g*32 + li];        // fd = li
        const float2 cs1 = ((const float2*)tab)[n_g*32 + 16 + li];   // fd = 16+li
        const float o0 = v0*cs0.x - v2*cs0.y;   // d = li
        const float o1 = v1*cs1.x - v3*cs1.y;   // d = 16+li
        const float o2 = v2*cs0.x + v0*cs0.y;   // d = 32+li
        const float o3 = v3*cs1.x + v1*cs1.y;   // d = 48+li
        unsigned short* drow = dstb + ((size_t)(bb*HEADS + h)*NTOT + (size_t)n_g)*64;
        drow[li]      = f2bf(o0);
        drow[16 + li] = f2bf(o1);
        drow[32 + li] = f2bf(o2);
        drow[48 + li] = f2bf(o3);
      }
    }
  } else {
    #pragma unroll
    for (int m = 0; m < 4; m++){
      #pragma unroll
      for (int r = 0; r < 4; r++){
        const int row = m0 + wr*64 + m*16 + lg*4 + r;
        const int bb = row >> 11, nn = row & 2047;
        const int n_g = nn + n_off;
        unsigned short* vbase = vt + (size_t)(bb*HEADS + h)*DH*NTOT + n_g;
        #pragma unroll
        for (int n = 0; n < 4; n++)
          vbase[(size_t)(n*16 + li)*NTOT] = f2bf(acc[m][n][r]);
      }
    }
  }
}

// ---------------- K3: MFMA segG: G = skT (64x256) x v (256x64), zc = row-sum(skT) ----------------
__global__ __launch_bounds__(256,2) void segG_kernel(const unsigned short* __restrict__ kb,
                                                     const unsigned short* __restrict__ vt,
                                                     float* __restrict__ G, float* __restrict__ zc){
  __shared__ unsigned short skT[64*264];   // [d][l], stride 264
  __shared__ unsigned short Vts[64*264];   // [e][l], stride 264
  const int blk = blockIdx.x;              // bh*16 + s
  const int bh = blk >> 4, s = blk & 15;
  const int tid = threadIdx.x;
  const int w = tid >> 6, lane = tid & 63;
  const int li = lane & 15, lg = lane >> 4;
  const size_t segoffb = ((size_t)bh * NTOT + (size_t)s * SEG) * DH;

  #pragma unroll
  for (int it = 0; it < 8; it++){
    const int idx = tid + it*256;          // 2048 b128 chunks
    const int e = idx >> 5, jc = idx & 31;
    *(u32x4*)(Vts + e*264 + jc*8) =
      *(const u32x4*)(vt + (size_t)bh*DH*NTOT + (size_t)e*NTOT + s*SEG + jc*8);
  }
  // skT = elu(k)+1 transposed; k already bf16
  #pragma unroll
  for (int it = 0; it < 8; it++){
    const int idx = tid + it*256;          // 2048 chunks of 8 dims
    const int l = idx >> 3, dc = idx & 7;
    bf16x8 kk = *(const bf16x8*)(kb + segoffb + (size_t)l*64 + dc*8);
    #pragma unroll
    for (int t2 = 0; t2 < 8; t2++){
      const float xx = bf2f((unsigned short)kk[t2]);
      skT[(dc*8 + t2)*264 + l] = f2bf(xx > 0.f ? xx + 1.f : __expf(xx));
    }
  }
  __syncthreads();

  // zc: 4 threads per d-row
  {
    const int d = tid >> 2, q = tid & 3;
    float zz = 0.f;
    #pragma unroll
    for (int u = 0; u < 8; u++){
      bf16x8 vv = *(const bf16x8*)(skT + d*264 + q*64 + u*8);
      #pragma unroll
      for (int t2 = 0; t2 < 8; t2++)
        zz += bf2f((unsigned short)vv[t2]);
    }
    zz += __shfl_xor(zz, 1, 64);
    zz += __shfl_xor(zz, 2, 64);
    if (q == 0) zc[(size_t)blk*64 + d] = zz;
  }

  f32x4 acc[4] = {};
  #pragma unroll
  for (int k0 = 0; k0 < 256; k0 += 32){
    bf16x8 af = *(const bf16x8*)(skT + (w*16 + li)*264 + k0 + lg*8);
    #pragma unroll
    for (int n = 0; n < 4; n++){
      bf16x8 bf = *(const bf16x8*)(Vts + (n*16 + li)*264 + k0 + lg*8);
      acc[n] = __builtin_amdgcn_mfma_f32_16x16x32_bf16(af, bf, acc[n], 0, 0, 0);
    }
  }
  float* Gout = G + (size_t)blk * DH * DH;
  #pragma unroll
  for (int n = 0; n < 4; n++)
    #pragma unroll
    for (int r = 0; r < 4; r++)
      Gout[(w*16 + lg*4 + r)*64 + n*16 + li] = acc[n][r];
}

// ---------------- K4: exclusive prefix over segments -> Mp, zp ----------------
__global__ __launch_bounds__(256) void prefix_kernel(const float* __restrict__ G,
                                                     const float* __restrict__ zc,
                                                     float* __restrict__ Mp, float* __restrict__ zp){
  const int bh = blockIdx.x, tid = threadIdx.x;
  float run[16];
  #pragma unroll
  for (int k = 0; k < 16; k++) run[k] = 0.f;
  for (int s = 0; s < NSEG; s++){
    const size_t base = ((size_t)bh * NSEG + s) * DH * DH;
    #pragma unroll
    for (int k = 0; k < 16; k++){
      Mp[base + tid + 256*k] = run[k];
      run[k] += G[base + tid + 256*k];
    }
  }
  if (tid < DH){
    float rz = 0.f;
    for (int s = 0; s < NSEG; s++){
      zp[((size_t)bh*NSEG + s)*DH + tid] = rz;
      rz += zc[((size_t)bh*NSEG + s)*DH + tid];
    }
  }
}

// ---------------- K5: MFMA flash-attention per segment + gated memory readout ----------------
__global__ __launch_bounds__(256,1) void attn_mfma_kernel(
    const unsigned short* __restrict__ qb, const unsigned short* __restrict__ kb,
    const unsigned short* __restrict__ vt, const float* __restrict__ Mp,
    const float* __restrict__ zp, const float* __restrict__ beta,
    float* __restrict__ out)
{
  __shared__ unsigned short Qs[256*72];    // [row][d], stride 72 bf16
  __shared__ unsigned short KSs[256*72];   // K, later SQ*g/denm
  __shared__ unsigned short Vts[64*264];   // [e][j], stride 264
  __shared__ unsigned short Ps[4*64*72];   // per-wave P [i][j]
  __shared__ unsigned short Mts[64*72];    // M^T [e][d]
  __shared__ float den_s[256];
  __shared__ float zsh[64];

  const int blk = blockIdx.x;
  const int s = blk & 15, bh = blk >> 4;
  const int h = bh & 15, b = bh >> 4;
  const int tid = threadIdx.x;
  const int w = tid >> 6, lane = tid & 63;
  const int li = lane & 15, lg = lane >> 4;
  const size_t segoffb = ((size_t)bh * NTOT + (size_t)s * SEG) * DH;

  // Q/K staging: direct bf16 copies (rows are 128B contiguous)
  #pragma unroll
  for (int it = 0; it < 8; it++){
    const int idx = tid + it*256;            // 2048 chunks of 16B
    const int row = idx >> 3, jc = idx & 7;
    *(u32x4*)(Qs  + row*72 + jc*8) = *(const u32x4*)(qb + segoffb + (size_t)row*64 + jc*8);
    *(u32x4*)(KSs + row*72 + jc*8) = *(const u32x4*)(kb + segoffb + (size_t)row*64 + jc*8);
  }
  #pragma unroll
  for (int it = 0; it < 8; it++){
    const int idx = tid + it*256;            // 2048 b128 chunks
    const int e = idx >> 5, jc = idx & 31;
    *(u32x4*)(Vts + e*264 + jc*8) =
      *(const u32x4*)(vt + (size_t)bh*DH*NTOT + (size_t)e*NTOT + s*SEG + jc*8);
  }
  #pragma unroll
  for (int it = 0; it < 16; it++){
    const int idx = tid + it*256;            // 4096 elems of Mp [d][e]
    const int d = idx >> 6, e = idx & 63;
    Mts[e*72 + d] = f2bf(Mp[(size_t)blk*4096 + d*64 + e]);
  }
  if (tid < 64) zsh[tid] = zp[(size_t)blk*64 + tid];
  __syncthreads();

  f32x4 o_acc[4][4] = {};
  float denr[4] = {0.f, 0.f, 0.f, 0.f};
  const int qrow0 = w*64;
  bf16x8 qf[4][2];
  #pragma unroll
  for (int it = 0; it < 4; it++)
    #pragma unroll
    for (int kb2 = 0; kb2 < 2; kb2++)
      qf[it][kb2] = *(const bf16x8*)(Qs + (qrow0 + it*16 + li)*72 + kb2*32 + lg*8);

  for (int c = 0; c <= w; c++){
    f32x4 st[4][4] = {};
    #pragma unroll
    for (int jt = 0; jt < 4; jt++){
      bf16x8 kf0 = *(const bf16x8*)(KSs + (c*64 + jt*16 + li)*72 + 0  + lg*8);
      bf16x8 kf1 = *(const bf16x8*)(KSs + (c*64 + jt*16 + li)*72 + 32 + lg*8);
      #pragma unroll
      for (int it = 0; it < 4; it++){
        st[jt][it] = __builtin_amdgcn_mfma_f32_16x16x32_bf16(kf0, qf[it][0], st[jt][it], 0, 0, 0);
        st[jt][it] = __builtin_amdgcn_mfma_f32_16x16x32_bf16(kf1, qf[it][1], st[jt][it], 0, 0, 0);
      }
    }
    const bool diag = (c == w);
    #pragma unroll
    for (int jt = 0; jt < 4; jt++){
      #pragma unroll
      for (int it = 0; it < 4; it++){
        f32x4 p = st[jt][it];
        unsigned pb[4];
        #pragma unroll
        for (int r = 0; r < 4; r++){
          float pe = __expf(p[r] * 0.125f);
          if (diag && (jt*16 + lg*4 + r > it*16 + li)) pe = 0.f;
          pb[r] = __builtin_bit_cast(unsigned, pe) & 0xFFFF0000u;   // bf16 truncation
          p[r] = __builtin_bit_cast(float, pb[r]);                  // value actually used in PV
        }
        denr[it] += (p[0] + p[1]) + (p[2] + p[3]);
        uint2 pkk;
        pkk.x = (pb[0] >> 16) | pb[1];
        pkk.y = (pb[2] >> 16) | pb[3];
        *(uint2*)(Ps + w*4608 + (it*16 + li)*72 + jt*16 + lg*4) = pkk;
      }
    }
    bf16x8 pf[4][2];
    #pragma unroll
    for (int it = 0; it < 4; it++)
      #pragma unroll
      for (int kb2 = 0; kb2 < 2; kb2++)
        pf[it][kb2] = *(const bf16x8*)(Ps + w*4608 + (it*16 + li)*72 + kb2*32 + lg*8);
    #pragma unroll
    for (int et = 0; et < 4; et++){
      bf16x8 vf0 = *(const bf16x8*)(Vts + (et*16 + li)*264 + c*64 + 0  + lg*8);
      bf16x8 vf1 = *(const bf16x8*)(Vts + (et*16 + li)*264 + c*64 + 32 + lg*8);
      #pragma unroll
      for (int it = 0; it < 4; it++){
        o_acc[it][et] = __builtin_amdgcn_mfma_f32_16x16x32_bf16(pf[it][0], vf0, o_acc[it][et], 0, 0, 0);
        o_acc[it][et] = __builtin_amdgcn_mfma_f32_16x16x32_bf16(pf[it][1], vf1, o_acc[it][et], 0, 0, 0);
      }
    }
  }

  #pragma unroll
  for (int it = 0; it < 4; it++){
    denr[it] += __shfl_xor(denr[it], 16, 64);
    denr[it] += __shfl_xor(denr[it], 32, 64);
  }
  if (lane < 16){
    #pragma unroll
    for (int it = 0; it < 4; it++) den_s[qrow0 + it*16 + lane] = denr[it];
  }
  const float gate = 1.f / (1.f + __expf(-beta[h]));
  __syncthreads();

  {
    const int i = tid;
    float sqv[64];
    float denm = 0.f;
    #pragma unroll
    for (int u = 0; u < 8; u++){
      bf16x8 qv = *(const bf16x8*)(Qs + i*72 + u*8);
      #pragma unroll
      for (int t2 = 0; t2 < 8; t2++){
        float x = bf2f((unsigned short)qv[t2]);
        float sq = x > 0.f ? x + 1.f : __expf(x);
        sqv[u*8 + t2] = sq;
        denm += sq * zsh[u*8 + t2];
      }
    }
    const float c2 = gate / (denm + 1e-6f);
    #pragma unroll
    for (int u = 0; u < 16; u++){
      uint2 pw;
      pw.x = f2bf(sqv[u*4]*c2)   | ((unsigned)f2bf(sqv[u*4+1]*c2) << 16);
      pw.y = f2bf(sqv[u*4+2]*c2) | ((unsigned)f2bf(sqv[u*4+3]*c2) << 16);
      *(uint2*)(KSs + i*72 + u*4) = pw;
    }
  }
  __syncthreads();

  #pragma unroll
  for (int it = 0; it < 4; it++){
    #pragma unroll
    for (int r = 0; r < 4; r++){
      const float c1 = (1.f - gate) / den_s[qrow0 + it*16 + lg*4 + r];
      #pragma unroll
      for (int et = 0; et < 4; et++) o_acc[it][et][r] *= c1;
    }
  }
  #pragma unroll
  for (int kb2 = 0; kb2 < 2; kb2++){
    bf16x8 mf[4];
    #pragma unroll
    for (int et = 0; et < 4; et++)
      mf[et] = *(const bf16x8*)(Mts + (et*16 + li)*72 + kb2*32 + lg*8);
    #pragma unroll
    for (int it = 0; it < 4; it++){
      bf16x8 sf = *(const bf16x8*)(KSs + (qrow0 + it*16 + li)*72 + kb2*32 + lg*8);
      #pragma unroll
      for (int et = 0; et < 4; et++)
        o_acc[it][et] = __builtin_amdgcn_mfma_f32_16x16x32_bf16(sf, mf[et], o_acc[it][et], 0, 0, 0);
    }
  }

  #pragma unroll
  for (int it = 0; it < 4; it++){
    #pragma unroll
    for (int r = 0; r < 4; r++){
      const int n_g = s*SEG + qrow0 + it*16 + lg*4 + r;
      size_t o;
      if (n_g >= NA) o = ((size_t)b * NX + (size_t)(n_g - NA)) * 1024 + h * 64;
      else           o = 4194304u + ((size_t)b * NA + (size_t)n_g) * 1024 + h * 64;
      #pragma unroll
      for (int et = 0; et < 4; et++)
        out[o + et*16 + li] = o_acc[it][et][r];
    }
  }
}

extern "C" void kernel_launch(void* const* d_in, const int* in_sizes, int n_in,
                              void* d_out, int out_size, void* d_ws, size_t ws_size,
                              hipStream_t stream)
{
  (void)ws_size;
  const int expect[9] = {4194304, 4194304, 3145728, 3145728, 1024, 1024, 1024, 1024, 16};
  bool ok = (n_in == 9);
  if (ok) for (int i = 0; i < 9; i++) if (in_sizes[i] != expect[i]) { ok = false; break; }
  float* out = (float*)d_out;
  if (!ok){
    zero_kernel<<<dim3((out_size + 255)/256), dim3(256), 0, stream>>>(out, out_size);
    return;
  }

  const float* x    = (const float*)d_in[0];
  const float* a    = (const float*)d_in[1];
  const float* wx   = (const float*)d_in[2];
  const float* wa   = (const float*)d_in[3];
  const float* gqx  = (const float*)d_in[4];
  const float* gkx  = (const float*)d_in[5];
  const float* gqa  = (const float*)d_in[6];
  const float* gka  = (const float*)d_in[7];
  const float* beta = (const float*)d_in[8];

  // Workspace layout (~97.8 MB)
  char* wsb = (char*)d_ws;
  unsigned short* qb  = (unsigned short*)wsb;     // 16,777,216 B  [bh][n][d] bf16
  unsigned short* kb  = qb + 8388608;             // 16,777,216 B
  unsigned short* vtb = kb + 8388608;             // 16,777,216 B  [bh][d][n] bf16
  unsigned short* Xb  = vtb + 8388608;            //  8,388,608 B
  unsigned short* Ab  = Xb + 4194304;             //  8,388,608 B
  unsigned short* WTx = Ab + 4194304;             //  6,291,456 B
  unsigned short* WTa = WTx + 3145728;            //  6,291,456 B
  float* ropetab = (float*)(WTa + 3145728);       //  1,048,576 B
  float* G   = ropetab + 262144;                  //  8,388,608 B
  float* Mp  = G + 2097152;                       //  8,388,608 B
  float* zc  = Mp + 2097152;                      //    131,072 B
  float* zpb = zc + 32768;                        //    131,072 B

  cvt_kernel<<<dim3(4096), dim3(256), 0, stream>>>(x, Xb, 1048576);
  cvt_kernel<<<dim3(4096), dim3(256), 0, stream>>>(a, Ab, 1048576);
  wtr_kernel<<<dim3(96,32), dim3(32,8), 0, stream>>>(wx, WTx);
  wtr_kernel<<<dim3(96,32), dim3(32,8), 0, stream>>>(wa, WTa);
  rope_tab_kernel<<<dim3(512), dim3(256), 0, stream>>>(ropetab);
  // a tokens occupy concatenated positions [0,2048); x tokens [2048,4096)
  gemm_qkv_kernel<<<dim3(24,32), dim3(256), 0, stream>>>(Xb, WTx, qb, kb, vtb, 2048, gqx, gkx, ropetab);
  gemm_qkv_kernel<<<dim3(24,32), dim3(256), 0, stream>>>(Ab, WTa, qb, kb, vtb, 0,    gqa, gka, ropetab);
  segG_kernel<<<dim3(512), dim3(256), 0, stream>>>(kb, vtb, G, zc);
  prefix_kernel<<<dim3(32), dim3(256), 0, stream>>>(G, zc, Mp, zpb);
  attn_mfma_kernel<<<dim3(512), dim3(256), 0, stream>>>(qb, kb, vtb, Mp, zpb, beta, out);
}

// Round 18
// 156.126 us; speedup vs baseline: 2.9771x; 1.0603x over previous
//
#include <hip/hip_runtime.h>

#define HEADS 16
#define DH    64
#define NA    2048
#define NX    2048
#define NTOT  4096
#define DIMK  1024
#define NQKV  3072
#define SEG   256
#define NSEG  16

typedef float          f32x4  __attribute__((ext_vector_type(4)));
typedef short          bf16x8 __attribute__((ext_vector_type(8)));
typedef unsigned int   u32x4  __attribute__((ext_vector_type(4)));

// f32 -> bf16 bits, round-to-nearest-even (finite inputs)
__device__ __forceinline__ unsigned short f2bf(float f){
  unsigned int u = __builtin_bit_cast(unsigned int, f);
  unsigned int r = 0x7fffu + ((u >> 16) & 1u);
  return (unsigned short)((u + r) >> 16);
}
__device__ __forceinline__ float bf2f(unsigned short u){
  return __builtin_bit_cast(float, ((unsigned int)u) << 16);
}

__global__ __launch_bounds__(256) void zero_kernel(float* __restrict__ out, int n){
  int i = blockIdx.x * 256 + threadIdx.x;
  if (i < n) out[i] = 0.f;
}

// ---------------- K0a: f32 -> bf16 elementwise ----------------
__global__ __launch_bounds__(256) void cvt_kernel(const float* __restrict__ src,
                                                  unsigned short* __restrict__ dst, int n4){
  int i = blockIdx.x * 256 + threadIdx.x;
  if (i >= n4) return;
  float4 v = ((const float4*)src)[i];
  ushort4 o;
  o.x = f2bf(v.x); o.y = f2bf(v.y); o.z = f2bf(v.z); o.w = f2bf(v.w);
  ((ushort4*)dst)[i] = o;
}

// ---------------- K0b: W [DIMK][NQKV] f32 -> WT [NQKV][DIMK] bf16 ----------------
__global__ __launch_bounds__(256) void wtr_kernel(const float* __restrict__ W,
                                                  unsigned short* __restrict__ WT){
  __shared__ float tile[32][33];
  int c0 = blockIdx.x * 32, k0 = blockIdx.y * 32;
  int tx = threadIdx.x, ty = threadIdx.y;
  #pragma unroll
  for (int i = 0; i < 32; i += 8) tile[ty+i][tx] = W[(size_t)(k0+ty+i)*NQKV + c0 + tx];
  __syncthreads();
  #pragma unroll
  for (int i = 0; i < 32; i += 8) WT[(size_t)(c0+ty+i)*DIMK + k0 + tx] = f2bf(tile[tx][ty+i]);
}

// ---------------- K0d: exact RoPE cos/sin table [n][fd][2], 131072 entries ----------------
__global__ __launch_bounds__(256) void rope_tab_kernel(float* __restrict__ tab){
  const int idx = blockIdx.x * 256 + threadIdx.x;   // < 131072
  const int n = idx >> 5, d = idx & 31;
  const float ang = (float)n * expf(-(float)d * 0.28782313662425572f);  // n * 10000^(-d/32)
  float sn, cs;
  sincosf(ang, &sn, &cs);
  float2 p; p.x = cs; p.y = sn;
  ((float2*)tab)[idx] = p;
}

// ---------------- K1: bf16 MFMA GEMM (global_load_lds staging) + fused norm/RoPE epilogue ----------------
// grid (24,32,2): z=0 -> x stream (n_off 2048), z=1 -> a stream (n_off 0)
__global__ __launch_bounds__(256,2) void gemm_qkv_kernel(
    const unsigned short* __restrict__ Xb, const unsigned short* __restrict__ Ab,
    const unsigned short* __restrict__ WTx, const unsigned short* __restrict__ WTa,
    unsigned short* __restrict__ qb, unsigned short* __restrict__ kb,
    unsigned short* __restrict__ vt,
    const float* __restrict__ gqx, const float* __restrict__ gkx,
    const float* __restrict__ gqa, const float* __restrict__ gka,
    const float* __restrict__ tab)
{
  __shared__ __align__(16) unsigned short As[128*32];
  __shared__ __align__(16) unsigned short Bs[128*32];
  const int strm = blockIdx.z;              // 0 = x, 1 = a
  const unsigned short* Xp = strm ? Ab  : Xb;
  const unsigned short* Wp = strm ? WTa : WTx;
  const float* gq = strm ? gqa : gqx;
  const float* gk = strm ? gka : gkx;
  const int n_off = strm ? 0 : NA;

  const int tid  = threadIdx.x;
  const int lane = tid & 63, w = tid >> 6;
  const int wr = w >> 1, wc = w & 1;
  const int li = lane & 15, lg = lane >> 4;
  const int m0 = blockIdx.y * 128, c0 = blockIdx.x * 128;

  // per-lane staging geometry (const across k-steps): 16 rows per 1KB instruction
  const int srow = lane >> 2;                 // 0..15 within the 16-row group
  const int sslot = lane & 3;

  f32x4 acc[4][4] = {};

  for (int k0 = 0; k0 < DIMK; k0 += 32){
    __syncthreads();
    // async global->LDS staging, width 16; LDS linear, source pre-swizzled (m173 pattern)
    #pragma unroll
    for (int jj = 0; jj < 2; jj++){
      const int j = 2*w + jj;                 // instruction group: rows j*16..j*16+15
      const int r = j*16 + srow;
      const int gs = sslot ^ (r & 3);
      __builtin_amdgcn_global_load_lds(
        (const __attribute__((address_space(1))) unsigned int*)(Xp + (size_t)(m0+r)*DIMK + k0 + gs*8),
        (__attribute__((address_space(3))) unsigned int*)(As + j*512), 16, 0, 0);
      __builtin_amdgcn_global_load_lds(
        (const __attribute__((address_space(1))) unsigned int*)(Wp + (size_t)(c0+r)*DIMK + k0 + gs*8),
        (__attribute__((address_space(3))) unsigned int*)(Bs + j*512), 16, 0, 0);
    }
    __syncthreads();
    bf16x8 af[4], bf[4];
    const int kc = lg;
    #pragma unroll
    for (int m = 0; m < 4; m++){
      const int r = wr*64 + m*16 + li;
      af[m] = *(const bf16x8*)(&As[r*32 + ((kc ^ (r & 3)) * 8)]);
    }
    #pragma unroll
    for (int n = 0; n < 4; n++){
      const int r = wc*64 + n*16 + li;
      bf[n] = *(const bf16x8*)(&Bs[r*32 + ((kc ^ (r & 3)) * 8)]);
    }
    #pragma unroll
    for (int m = 0; m < 4; m++)
      #pragma unroll
      for (int n = 0; n < 4; n++)
        acc[m][n] = __builtin_amdgcn_mfma_f32_16x16x32_bf16(af[m], bf[n], acc[m][n], 0, 0, 0);
  }

  const int colbase = c0 + wc*64;           // multiple of 64; one head per wave
  const int which = colbase >> 10;          // 0=q, 1=k, 2=v (wave-uniform)
  const int h = (colbase >> 6) & 15;

  if (which < 2){
    const float* gv = (which == 0) ? gq : gk;
    unsigned short* dstb = (which == 0) ? qb : kb;
    float gl[4];
    #pragma unroll
    for (int n = 0; n < 4; n++) gl[n] = gv[h*64 + n*16 + li];
    #pragma unroll
    for (int m = 0; m < 4; m++){
      #pragma unroll
      for (int r = 0; r < 4; r++){
        float ss = acc[m][0][r]*acc[m][0][r] + acc[m][1][r]*acc[m][1][r]
                 + acc[m][2][r]*acc[m][2][r] + acc[m][3][r]*acc[m][3][r];
        ss += __shfl_xor(ss, 1, 64);
        ss += __shfl_xor(ss, 2, 64);
        ss += __shfl_xor(ss, 4, 64);
        ss += __shfl_xor(ss, 8, 64);
        const float sc = 8.0f / fmaxf(sqrtf(ss), 1e-12f);
        float v0 = acc[m][0][r]*sc*gl[0], v1 = acc[m][1][r]*sc*gl[1];
        float v2 = acc[m][2][r]*sc*gl[2], v3 = acc[m][3][r]*sc*gl[3];
        const int row = m0 + wr*64 + m*16 + lg*4 + r;
        const int bb = row >> 11, nn = row & 2047;
        const int n_g = nn + n_off;
        const float2 cs0 = ((const float2*)tab)[n_g*32 + li];        // fd = li
        const float2 cs1 = ((const float2*)tab)[n_g*32 + 16 + li];   // fd = 16+li
        const float o0 = v0*cs0.x - v2*cs0.y;   // d = li
        const float o1 = v1*cs1.x - v3*cs1.y;   // d = 16+li
        const float o2 = v2*cs0.x + v0*cs0.y;   // d = 32+li
        const float o3 = v3*cs1.x + v1*cs1.y;   // d = 48+li
        unsigned short* drow = dstb + ((size_t)(bb*HEADS + h)*NTOT + (size_t)n_g)*64;
        drow[li]      = f2bf(o0);
        drow[16 + li] = f2bf(o1);
        drow[32 + li] = f2bf(o2);
        drow[48 + li] = f2bf(o3);
      }
    }
  } else {
    #pragma unroll
    for (int m = 0; m < 4; m++){
      #pragma unroll
      for (int r = 0; r < 4; r++){
        const int row = m0 + wr*64 + m*16 + lg*4 + r;
        const int bb = row >> 11, nn = row & 2047;
        const int n_g = nn + n_off;
        unsigned short* vbase = vt + (size_t)(bb*HEADS + h)*DH*NTOT + n_g;
        #pragma unroll
        for (int n = 0; n < 4; n++)
          vbase[(size_t)(n*16 + li)*NTOT] = f2bf(acc[m][n][r]);
      }
    }
  }
}

// ---------------- K3: MFMA segG: G = skT (64x256) x v (256x64), zc = row-sum(skT) ----------------
__global__ __launch_bounds__(256,2) void segG_kernel(const unsigned short* __restrict__ kb,
                                                     const unsigned short* __restrict__ vt,
                                                     float* __restrict__ G, float* __restrict__ zc){
  __shared__ unsigned short skT[64*264];   // [d][l], stride 264
  __shared__ unsigned short Vts[64*264];   // [e][l], stride 264
  const int blk = blockIdx.x;              // bh*16 + s
  const int bh = blk >> 4, s = blk & 15;
  const int tid = threadIdx.x;
  const int w = tid >> 6, lane = tid & 63;
  const int li = lane & 15, lg = lane >> 4;
  const size_t segoffb = ((size_t)bh * NTOT + (size_t)s * SEG) * DH;

  #pragma unroll
  for (int it = 0; it < 8; it++){
    const int idx = tid + it*256;          // 2048 b128 chunks
    const int e = idx >> 5, jc = idx & 31;
    *(u32x4*)(Vts + e*264 + jc*8) =
      *(const u32x4*)(vt + (size_t)bh*DH*NTOT + (size_t)e*NTOT + s*SEG + jc*8);
  }
  // skT = elu(k)+1 transposed; k already bf16
  #pragma unroll
  for (int it = 0; it < 8; it++){
    const int idx = tid + it*256;          // 2048 chunks of 8 dims
    const int l = idx >> 3, dc = idx & 7;
    bf16x8 kk = *(const bf16x8*)(kb + segoffb + (size_t)l*64 + dc*8);
    #pragma unroll
    for (int t2 = 0; t2 < 8; t2++){
      const float xx = bf2f((unsigned short)kk[t2]);
      skT[(dc*8 + t2)*264 + l] = f2bf(xx > 0.f ? xx + 1.f : __expf(xx));
    }
  }
  __syncthreads();

  // zc: 4 threads per d-row
  {
    const int d = tid >> 2, q = tid & 3;
    float zz = 0.f;
    #pragma unroll
    for (int u = 0; u < 8; u++){
      bf16x8 vv = *(const bf16x8*)(skT + d*264 + q*64 + u*8);
      #pragma unroll
      for (int t2 = 0; t2 < 8; t2++)
        zz += bf2f((unsigned short)vv[t2]);
    }
    zz += __shfl_xor(zz, 1, 64);
    zz += __shfl_xor(zz, 2, 64);
    if (q == 0) zc[(size_t)blk*64 + d] = zz;
  }

  f32x4 acc[4] = {};
  #pragma unroll
  for (int k0 = 0; k0 < 256; k0 += 32){
    bf16x8 af = *(const bf16x8*)(skT + (w*16 + li)*264 + k0 + lg*8);
    #pragma unroll
    for (int n = 0; n < 4; n++){
      bf16x8 bf = *(const bf16x8*)(Vts + (n*16 + li)*264 + k0 + lg*8);
      acc[n] = __builtin_amdgcn_mfma_f32_16x16x32_bf16(af, bf, acc[n], 0, 0, 0);
    }
  }
  float* Gout = G + (size_t)blk * DH * DH;
  #pragma unroll
  for (int n = 0; n < 4; n++)
    #pragma unroll
    for (int r = 0; r < 4; r++)
      Gout[(w*16 + lg*4 + r)*64 + n*16 + li] = acc[n][r];
}

// ---------------- K4: exclusive prefix over segments -> Mp, zp ----------------
__global__ __launch_bounds__(256) void prefix_kernel(const float* __restrict__ G,
                                                     const float* __restrict__ zc,
                                                     float* __restrict__ Mp, float* __restrict__ zp){
  const int bh = blockIdx.x, tid = threadIdx.x;
  float run[16];
  #pragma unroll
  for (int k = 0; k < 16; k++) run[k] = 0.f;
  for (int s = 0; s < NSEG; s++){
    const size_t base = ((size_t)bh * NSEG + s) * DH * DH;
    #pragma unroll
    for (int k = 0; k < 16; k++){
      Mp[base + tid + 256*k] = run[k];
      run[k] += G[base + tid + 256*k];
    }
  }
  if (tid < DH){
    float rz = 0.f;
    for (int s = 0; s < NSEG; s++){
      zp[((size_t)bh*NSEG + s)*DH + tid] = rz;
      rz += zc[((size_t)bh*NSEG + s)*DH + tid];
    }
  }
}

// ---------------- K5: MFMA flash-attention per segment + gated memory readout ----------------
__global__ __launch_bounds__(256,1) void attn_mfma_kernel(
    const unsigned short* __restrict__ qb, const unsigned short* __restrict__ kb,
    const unsigned short* __restrict__ vt, const float* __restrict__ Mp,
    const float* __restrict__ zp, const float* __restrict__ beta,
    float* __restrict__ out)
{
  __shared__ unsigned short Qs[256*72];    // [row][d], stride 72 bf16
  __shared__ unsigned short KSs[256*72];   // K, later SQ*g/denm
  __shared__ unsigned short Vts[64*264];   // [e][j], stride 264
  __shared__ unsigned short Ps[4*64*72];   // per-wave P [i][j]
  __shared__ unsigned short Mts[64*72];    // M^T [e][d]
  __shared__ float den_s[256];
  __shared__ float zsh[64];

  const int blk = blockIdx.x;
  const int s = blk & 15, bh = blk >> 4;
  const int h = bh & 15, b = bh >> 4;
  const int tid = threadIdx.x;
  const int w = tid >> 6, lane = tid & 63;
  const int li = lane & 15, lg = lane >> 4;
  const size_t segoffb = ((size_t)bh * NTOT + (size_t)s * SEG) * DH;

  // Q/K staging: direct bf16 copies (rows are 128B contiguous)
  #pragma unroll
  for (int it = 0; it < 8; it++){
    const int idx = tid + it*256;            // 2048 chunks of 16B
    const int row = idx >> 3, jc = idx & 7;
    *(u32x4*)(Qs  + row*72 + jc*8) = *(const u32x4*)(qb + segoffb + (size_t)row*64 + jc*8);
    *(u32x4*)(KSs + row*72 + jc*8) = *(const u32x4*)(kb + segoffb + (size_t)row*64 + jc*8);
  }
  #pragma unroll
  for (int it = 0; it < 8; it++){
    const int idx = tid + it*256;            // 2048 b128 chunks
    const int e = idx >> 5, jc = idx & 31;
    *(u32x4*)(Vts + e*264 + jc*8) =
      *(const u32x4*)(vt + (size_t)bh*DH*NTOT + (size_t)e*NTOT + s*SEG + jc*8);
  }
  #pragma unroll
  for (int it = 0; it < 16; it++){
    const int idx = tid + it*256;            // 4096 elems of Mp [d][e]
    const int d = idx >> 6, e = idx & 63;
    Mts[e*72 + d] = f2bf(Mp[(size_t)blk*4096 + d*64 + e]);
  }
  if (tid < 64) zsh[tid] = zp[(size_t)blk*64 + tid];
  __syncthreads();

  f32x4 o_acc[4][4] = {};
  float denr[4] = {0.f, 0.f, 0.f, 0.f};
  const int qrow0 = w*64;
  bf16x8 qf[4][2];
  #pragma unroll
  for (int it = 0; it < 4; it++)
    #pragma unroll
    for (int kb2 = 0; kb2 < 2; kb2++)
      qf[it][kb2] = *(const bf16x8*)(Qs + (qrow0 + it*16 + li)*72 + kb2*32 + lg*8);

  for (int c = 0; c <= w; c++){
    f32x4 st[4][4] = {};
    #pragma unroll
    for (int jt = 0; jt < 4; jt++){
      bf16x8 kf0 = *(const bf16x8*)(KSs + (c*64 + jt*16 + li)*72 + 0  + lg*8);
      bf16x8 kf1 = *(const bf16x8*)(KSs + (c*64 + jt*16 + li)*72 + 32 + lg*8);
      #pragma unroll
      for (int it = 0; it < 4; it++){
        st[jt][it] = __builtin_amdgcn_mfma_f32_16x16x32_bf16(kf0, qf[it][0], st[jt][it], 0, 0, 0);
        st[jt][it] = __builtin_amdgcn_mfma_f32_16x16x32_bf16(kf1, qf[it][1], st[jt][it], 0, 0, 0);
      }
    }
    const bool diag = (c == w);
    #pragma unroll
    for (int jt = 0; jt < 4; jt++){
      #pragma unroll
      for (int it = 0; it < 4; it++){
        f32x4 p = st[jt][it];
        unsigned pb[4];
        #pragma unroll
        for (int r = 0; r < 4; r++){
          float pe = __expf(p[r] * 0.125f);
          if (diag && (jt*16 + lg*4 + r > it*16 + li)) pe = 0.f;
          pb[r] = __builtin_bit_cast(unsigned, pe) & 0xFFFF0000u;   // bf16 truncation
          p[r] = __builtin_bit_cast(float, pb[r]);                  // value actually used in PV
        }
        denr[it] += (p[0] + p[1]) + (p[2] + p[3]);
        uint2 pkk;
        pkk.x = (pb[0] >> 16) | pb[1];
        pkk.y = (pb[2] >> 16) | pb[3];
        *(uint2*)(Ps + w*4608 + (it*16 + li)*72 + jt*16 + lg*4) = pkk;
      }
    }
    bf16x8 pf[4][2];
    #pragma unroll
    for (int it = 0; it < 4; it++)
      #pragma unroll
      for (int kb2 = 0; kb2 < 2; kb2++)
        pf[it][kb2] = *(const bf16x8*)(Ps + w*4608 + (it*16 + li)*72 + kb2*32 + lg*8);
    #pragma unroll
    for (int et = 0; et < 4; et++){
      bf16x8 vf0 = *(const bf16x8*)(Vts + (et*16 + li)*264 + c*64 + 0  + lg*8);
      bf16x8 vf1 = *(const bf16x8*)(Vts + (et*16 + li)*264 + c*64 + 32 + lg*8);
      #pragma unroll
      for (int it = 0; it < 4; it++){
        o_acc[it][et] = __builtin_amdgcn_mfma_f32_16x16x32_bf16(pf[it][0], vf0, o_acc[it][et], 0, 0, 0);
        o_acc[it][et] = __builtin_amdgcn_mfma_f32_16x16x32_bf16(pf[it][1], vf1, o_acc[it][et], 0, 0, 0);
      }
    }
  }

  #pragma unroll
  for (int it = 0; it < 4; it++){
    denr[it] += __shfl_xor(denr[it], 16, 64);
    denr[it] += __shfl_xor(denr[it], 32, 64);
  }
  if (lane < 16){
    #pragma unroll
    for (int it = 0; it < 4; it++) den_s[qrow0 + it*16 + lane] = denr[it];
  }
  const float gate = 1.f / (1.f + __expf(-beta[h]));
  __syncthreads();

  {
    const int i = tid;
    float sqv[64];
    float denm = 0.f;
    #pragma unroll
    for (int u = 0; u < 8; u++){
      bf16x8 qv = *(const bf16x8*)(Qs + i*72 + u*8);
      #pragma unroll
      for (int t2 = 0; t2 < 8; t2++){
        float x = bf2f((unsigned short)qv[t2]);
        float sq = x > 0.f ? x + 1.f : __expf(x);
        sqv[u*8 + t2] = sq;
        denm += sq * zsh[u*8 + t2];
      }
    }
    const float c2 = gate / (denm + 1e-6f);
    #pragma unroll
    for (int u = 0; u < 16; u++){
      uint2 pw;
      pw.x = f2bf(sqv[u*4]*c2)   | ((unsigned)f2bf(sqv[u*4+1]*c2) << 16);
      pw.y = f2bf(sqv[u*4+2]*c2) | ((unsigned)f2bf(sqv[u*4+3]*c2) << 16);
      *(uint2*)(KSs + i*72 + u*4) = pw;
    }
  }
  __syncthreads();

  #pragma unroll
  for (int it = 0; it < 4; it++){
    #pragma unroll
    for (int r = 0; r < 4; r++){
      const float c1 = (1.f - gate) / den_s[qrow0 + it*16 + lg*4 + r];
      #pragma unroll
      for (int et = 0; et < 4; et++) o_acc[it][et][r] *= c1;
    }
  }
  #pragma unroll
  for (int kb2 = 0; kb2 < 2; kb2++){
    bf16x8 mf[4];
    #pragma unroll
    for (int et = 0; et < 4; et++)
      mf[et] = *(const bf16x8*)(Mts + (et*16 + li)*72 + kb2*32 + lg*8);
    #pragma unroll
    for (int it = 0; it < 4; it++){
      bf16x8 sf = *(const bf16x8*)(KSs + (qrow0 + it*16 + li)*72 + kb2*32 + lg*8);
      #pragma unroll
      for (int et = 0; et < 4; et++)
        o_acc[it][et] = __builtin_amdgcn_mfma_f32_16x16x32_bf16(sf, mf[et], o_acc[it][et], 0, 0, 0);
    }
  }

  #pragma unroll
  for (int it = 0; it < 4; it++){
    #pragma unroll
    for (int r = 0; r < 4; r++){
      const int n_g = s*SEG + qrow0 + it*16 + lg*4 + r;
      size_t o;
      if (n_g >= NA) o = ((size_t)b * NX + (size_t)(n_g - NA)) * 1024 + h * 64;
      else           o = 4194304u + ((size_t)b * NA + (size_t)n_g) * 1024 + h * 64;
      #pragma unroll
      for (int et = 0; et < 4; et++)
        out[o + et*16 + li] = o_acc[it][et][r];
    }
  }
}

extern "C" void kernel_launch(void* const* d_in, const int* in_sizes, int n_in,
                              void* d_out, int out_size, void* d_ws, size_t ws_size,
                              hipStream_t stream)
{
  (void)ws_size;
  const int expect[9] = {4194304, 4194304, 3145728, 3145728, 1024, 1024, 1024, 1024, 16};
  bool ok = (n_in == 9);
  if (ok) for (int i = 0; i < 9; i++) if (in_sizes[i] != expect[i]) { ok = false; break; }
  float* out = (float*)d_out;
  if (!ok){
    zero_kernel<<<dim3((out_size + 255)/256), dim3(256), 0, stream>>>(out, out_size);
    return;
  }

  const float* x    = (const float*)d_in[0];
  const float* a    = (const float*)d_in[1];
  const float* wx   = (const float*)d_in[2];
  const float* wa   = (const float*)d_in[3];
  const float* gqx  = (const float*)d_in[4];
  const float* gkx  = (const float*)d_in[5];
  const float* gqa  = (const float*)d_in[6];
  const float* gka  = (const float*)d_in[7];
  const float* beta = (const float*)d_in[8];

  // Workspace layout (~97.8 MB)
  char* wsb = (char*)d_ws;
  unsigned short* qb  = (unsigned short*)wsb;     // 16,777,216 B  [bh][n][d] bf16
  unsigned short* kb  = qb + 8388608;             // 16,777,216 B
  unsigned short* vtb = kb + 8388608;             // 16,777,216 B  [bh][d][n] bf16
  unsigned short* Xb  = vtb + 8388608;            //  8,388,608 B
  unsigned short* Ab  = Xb + 4194304;             //  8,388,608 B
  unsigned short* WTx = Ab + 4194304;             //  6,291,456 B
  unsigned short* WTa = WTx + 3145728;            //  6,291,456 B
  float* ropetab = (float*)(WTa + 3145728);       //  1,048,576 B
  float* G   = ropetab + 262144;                  //  8,388,608 B
  float* Mp  = G + 2097152;                       //  8,388,608 B
  float* zc  = Mp + 2097152;                      //    131,072 B
  float* zpb = zc + 32768;                        //    131,072 B

  cvt_kernel<<<dim3(4096), dim3(256), 0, stream>>>(x, Xb, 1048576);
  cvt_kernel<<<dim3(4096), dim3(256), 0, stream>>>(a, Ab, 1048576);
  wtr_kernel<<<dim3(96,32), dim3(32,8), 0, stream>>>(wx, WTx);
  wtr_kernel<<<dim3(96,32), dim3(32,8), 0, stream>>>(wa, WTa);
  rope_tab_kernel<<<dim3(512), dim3(256), 0, stream>>>(ropetab);
  // a tokens occupy concatenated positions [0,2048); x tokens [2048,4096)
  gemm_qkv_kernel<<<dim3(24,32,2), dim3(256), 0, stream>>>(Xb, Ab, WTx, WTa, qb, kb, vtb,
                                                           gqx, gkx, gqa, gka, ropetab);
  segG_kernel<<<dim3(512), dim3(256), 0, stream>>>(kb, vtb, G, zc);
  prefix_kernel<<<dim3(32), dim3(256), 0, stream>>>(G, zc, Mp, zpb);
  attn_mfma_kernel<<<dim3(512), dim3(256), 0, stream>>>(qb, kb, vtb, Mp, zpb, beta, out);
}